// Round 1
// baseline (1693.651 us; speedup 1.0000x reference)
//
#include <hip/hip_runtime.h>
#include <cstdint>
#include <cstddef>

#define EPSF 1e-5f

// ---------------------------------------------------------------- deg / norm
__global__ void deg_kernel(const int* __restrict__ col, const float* __restrict__ w,
                           float* __restrict__ deg, int E) {
    int e = blockIdx.x * blockDim.x + threadIdx.x;
    if (e < E) atomicAdd(&deg[col[e]], w[e]);
}

// in-place deg -> dinv
__global__ void dinv_kernel(float* __restrict__ deg, int N) {
    int i = blockIdx.x * blockDim.x + threadIdx.x;
    if (i < N) { float d = deg[i]; deg[i] = (d > 0.f) ? rsqrtf(d) : 0.f; }
}

__global__ void norm_kernel(const int* __restrict__ row, const int* __restrict__ col,
                            const float* __restrict__ w, const float* __restrict__ dinv,
                            float* __restrict__ norm, int E) {
    int e = blockIdx.x * blockDim.x + threadIdx.x;
    if (e < E) norm[e] = dinv[row[e]] * dinv[col[e]] * w[e];
}

// ---------------------------------------------------------------- GEMM: Y = X @ W^T
// X [N,128], W [128,128] row-major, Y[n,j] = sum_d X[n,d]*W[j,d].
// 64 rows/block, 512 threads, 4x4 register tile. Safe to call with Y == X
// (each block stages its own rows into LDS before any write).
__global__ __launch_bounds__(512) void gemm128(const float* __restrict__ X,
                                               const float* __restrict__ W,
                                               float* __restrict__ Y, int N) {
    __shared__ float WT[128][132];  // WT[d][j] = W[j][d]; stride 132: 16B-aligned rows, bank-spread
    __shared__ float XT[128][68];   // XT[d][nn] = X[n0+nn][d]; stride 68: 16B-aligned rows

    const int t  = threadIdx.x;
    const int n0 = blockIdx.x * 64;

    for (int i = t; i < 128 * 128; i += 512) {
        int j = i >> 7, d = i & 127;
        WT[d][j] = W[i];
    }
    for (int i = t; i < 64 * 128; i += 512) {
        int nn = i >> 7, d = i & 127;
        int n = n0 + nn;
        XT[d][nn] = (n < N) ? X[(size_t)n * 128 + d] : 0.f;
    }
    __syncthreads();

    const int j0  = (t & 31) * 4;
    const int nn0 = (t >> 5) * 4;
    float acc[4][4] = {};

    for (int d = 0; d < 128; ++d) {
        float wv[4], xv[4];
        *(float4*)wv = *(const float4*)&WT[d][j0];
        *(float4*)xv = *(const float4*)&XT[d][nn0];
#pragma unroll
        for (int a = 0; a < 4; ++a)
#pragma unroll
            for (int b = 0; b < 4; ++b)
                acc[a][b] = fmaf(xv[a], wv[b], acc[a][b]);
    }

#pragma unroll
    for (int a = 0; a < 4; ++a) {
        int n = n0 + nn0 + a;
        if (n < N) {
            float4 v = make_float4(acc[a][0], acc[a][1], acc[a][2], acc[a][3]);
            *(float4*)&Y[(size_t)n * 128 + j0] = v;
        }
    }
}

// ---------------------------------------------------------------- scatter-add conv
// one wave per edge; lane L handles feature L and L+64
__global__ __launch_bounds__(256) void agg_atomic(const float* __restrict__ Hin,
                                                  const int* __restrict__ row,
                                                  const int* __restrict__ col,
                                                  const float* __restrict__ norm,
                                                  float* __restrict__ Hout, int E) {
    int e = blockIdx.x * 4 + (threadIdx.x >> 6);
    if (e >= E) return;
    int lane = threadIdx.x & 63;
    int r = row[e], c = col[e];
    float nw = norm[e];
    if (nw != 0.f) {
        const float* src = Hin + (size_t)r * 128;
        float*       dst = Hout + (size_t)c * 128;
        atomicAdd(&dst[lane],      nw * src[lane]);
        atomicAdd(&dst[lane + 64], nw * src[lane + 64]);
    }
}

// ---------------------------------------------------------------- batchnorm
// sums[j] = sum_n H[n,j]; sums[128+j] = sum_n H[n,j]^2
__global__ __launch_bounds__(256) void bn_stats(const float* __restrict__ H,
                                                float* __restrict__ sums, int N) {
    int j = threadIdx.x & 127;
    float s = 0.f, s2 = 0.f;
    for (int n = blockIdx.x * 2 + (threadIdx.x >> 7); n < N; n += gridDim.x * 2) {
        float v = H[(size_t)n * 128 + j];
        s += v; s2 += v * v;
    }
    atomicAdd(&sums[j], s);
    atomicAdd(&sums[128 + j], s2);
}

// Y = relu((H - mu) * rsqrt(var + eps)), float4 over columns
__global__ __launch_bounds__(256) void bn_apply(const float* __restrict__ H,
                                                const float* __restrict__ sums,
                                                float* __restrict__ Y, int N, float invN) {
    int idx = blockIdx.x * blockDim.x + threadIdx.x;  // over N*32
    if (idx >= N * 32) return;
    int j0 = (idx & 31) * 4;
    float4 h = *(const float4*)&H[(size_t)idx * 4];
    float o[4];
    const float* hv = &h.x;
#pragma unroll
    for (int k = 0; k < 4; ++k) {
        float mu  = sums[j0 + k] * invN;
        float var = sums[128 + j0 + k] * invN - mu * mu;
        float v   = (hv[k] - mu) * rsqrtf(var + EPSF);
        o[k] = fmaxf(v, 0.f);
    }
    *(float4*)&Y[(size_t)idx * 4] = *(float4*)o;
}

// out[n,j] = b1[j] (final conv atomics accumulate on top)
__global__ __launch_bounds__(256) void init_out(float* __restrict__ out,
                                                const float* __restrict__ b1, int N) {
    int idx = blockIdx.x * blockDim.x + threadIdx.x;  // over N*32
    if (idx >= N * 32) return;
    int j0 = (idx & 31) * 4;
    *(float4*)&out[(size_t)idx * 4] = *(const float4*)&b1[j0];
}

// ---------------------------------------------------------------- launch
extern "C" void kernel_launch(void* const* d_in, const int* in_sizes, int n_in,
                              void* d_out, int out_size, void* d_ws, size_t ws_size,
                              hipStream_t stream) {
    const float* x  = (const float*)d_in[0];
    const int*   ei = (const int*)d_in[1];
    const float* ew = (const float*)d_in[2];
    const float* W0 = (const float*)d_in[3];
    const float* W1 = (const float*)d_in[5];
    const float* b1 = (const float*)d_in[6];

    const int N = in_sizes[0] / 128;
    const int E = in_sizes[2];
    const int* row = ei;
    const int* col = ei + E;

    // workspace carve-up (256B aligned)
    uintptr_t base = (uintptr_t)d_ws;
    auto alloc = [&](size_t bytes) {
        uintptr_t p = base;
        base += (bytes + 255) & ~(size_t)255;
        return (void*)p;
    };
    float* deg  = (float*)alloc((size_t)N * 4);          // becomes dinv in-place
    float* norm = (float*)alloc((size_t)E * 4);
    float* hA   = (float*)alloc((size_t)N * 128 * 4);
    float* sums = (float*)alloc(256 * 4);
    float* out  = (float*)d_out;
    (void)ws_size; (void)n_in; (void)out_size;

    const float invN = 1.f / (float)N;

    // --- degree -> dinv -> per-edge norm
    hipMemsetAsync(deg, 0, (size_t)N * 4, stream);
    deg_kernel <<<(E + 255) / 256, 256, 0, stream>>>(col, ew, deg, E);
    dinv_kernel<<<(N + 255) / 256, 256, 0, stream>>>(deg, N);
    norm_kernel<<<(E + 255) / 256, 256, 0, stream>>>(row, col, ew, deg, norm, E);

    // --- layer 0: hA = x @ W0^T
    gemm128<<<(N + 63) / 64, 512, 0, stream>>>(x, W0, hA, N);

    // --- conv 1: out(buf) = scatter(hA[row]*norm -> col)
    hipMemsetAsync(out, 0, (size_t)N * 128 * 4, stream);
    agg_atomic<<<(E + 3) / 4, 256, 0, stream>>>(hA, row, col, norm, out, E);

    // --- batchnorm + relu: hA = relu(BN(out))   (b0 cancels inside BN)
    hipMemsetAsync(sums, 0, 256 * 4, stream);
    bn_stats<<<512, 256, 0, stream>>>(out, sums, N);
    bn_apply<<<(N * 32 + 255) / 256, 256, 0, stream>>>(out, sums, hA, N, invN);

    // --- layer 1: hA = hA @ W1^T (in-place safe)
    gemm128<<<(N + 63) / 64, 512, 0, stream>>>(hA, W1, hA, N);

    // --- conv 2 (+ b1): out = b1 + scatter(hA[row]*norm -> col)
    init_out<<<(N * 32 + 255) / 256, 256, 0, stream>>>(out, b1, N);
    agg_atomic<<<(E + 3) / 4, 256, 0, stream>>>(hA, row, col, norm, out, E);
}

// Round 3
// 905.321 us; speedup vs baseline: 1.8708x; 1.8708x over previous
//
#include <hip/hip_runtime.h>
#include <cstdint>
#include <cstddef>

#define EPSF 1e-5f

// ---------------------------------------------------------------- deg + histogram (fused)
__global__ void deg_hist_kernel(const int* __restrict__ col, const float* __restrict__ w,
                                float* __restrict__ deg, int* __restrict__ cnt, int E) {
    int e = blockIdx.x * blockDim.x + threadIdx.x;
    if (e < E) {
        int c = col[e];
        atomicAdd(&deg[c], w[e]);
        atomicAdd(&cnt[c], 1);
    }
}

// in-place deg -> dinv
__global__ void dinv_kernel(float* __restrict__ deg, int N) {
    int i = blockIdx.x * blockDim.x + threadIdx.x;
    if (i < N) { float d = deg[i]; deg[i] = (d > 0.f) ? rsqrtf(d) : 0.f; }
}

// ---------------------------------------------------------------- single-block exclusive scan
// cnt[N] -> rs[N+1] (rs[N] = total). 1024 threads, each owns a contiguous chunk.
__global__ __launch_bounds__(1024) void scan_exclusive(const int* __restrict__ cnt,
                                                       int* __restrict__ rs, int N) {
    __shared__ int part[1024];
    const int t = threadIdx.x;
    const int chunk = (N + 1023) >> 10;
    const int base = t * chunk;
    const int lim = (base + chunk < N) ? base + chunk : N;

    int s = 0;
    for (int i = base; i < lim; ++i) s += cnt[i];
    part[t] = s;
    __syncthreads();
    for (int off = 1; off < 1024; off <<= 1) {
        int v = (t >= off) ? part[t - off] : 0;
        __syncthreads();
        part[t] += v;
        __syncthreads();
    }
    int run = (t == 0) ? 0 : part[t - 1];
    for (int i = base; i < lim; ++i) { rs[i] = run; run += cnt[i]; }
    if (base < N && base + chunk >= N) rs[N] = run;  // exactly one thread
}

// ---------------------------------------------------------------- scatter edges into CSR slots
__global__ void csr_scatter_kernel(const int* __restrict__ row, const int* __restrict__ col,
                                   const float* __restrict__ w, const float* __restrict__ dinv,
                                   int* __restrict__ cursor,
                                   int* __restrict__ srow, float* __restrict__ snorm, int E) {
    int e = blockIdx.x * blockDim.x + threadIdx.x;
    if (e < E) {
        int r = row[e], c = col[e];
        int pos = atomicAdd(&cursor[c], 1);
        srow[pos]  = r;
        snorm[pos] = dinv[r] * dinv[c] * w[e];
    }
}

// ---------------------------------------------------------------- GEMM: Y = X @ W^T
// X [N,128], W [128,128] row-major. 64 rows/block, 512 threads, 4x4 register tile.
// Safe with Y == X (block stages its rows to LDS before writing).
__global__ __launch_bounds__(512) void gemm128(const float* __restrict__ X,
                                               const float* __restrict__ W,
                                               float* __restrict__ Y, int N) {
    __shared__ float WT[128][132];
    __shared__ float XT[128][68];

    const int t  = threadIdx.x;
    const int n0 = blockIdx.x * 64;

    for (int i = t; i < 128 * 128; i += 512) {
        int j = i >> 7, d = i & 127;
        WT[d][j] = W[i];
    }
    for (int i = t; i < 64 * 128; i += 512) {
        int nn = i >> 7, d = i & 127;
        int n = n0 + nn;
        XT[d][nn] = (n < N) ? X[(size_t)n * 128 + d] : 0.f;
    }
    __syncthreads();

    const int j0  = (t & 31) * 4;
    const int nn0 = (t >> 5) * 4;
    float acc[4][4] = {};

    for (int d = 0; d < 128; ++d) {
        float wv[4], xv[4];
        *(float4*)wv = *(const float4*)&WT[d][j0];
        *(float4*)xv = *(const float4*)&XT[d][nn0];
#pragma unroll
        for (int a = 0; a < 4; ++a)
#pragma unroll
            for (int b = 0; b < 4; ++b)
                acc[a][b] = fmaf(xv[a], wv[b], acc[a][b]);
    }

#pragma unroll
    for (int a = 0; a < 4; ++a) {
        int n = n0 + nn0 + a;
        if (n < N) {
            float4 v = make_float4(acc[a][0], acc[a][1], acc[a][2], acc[a][3]);
            *(float4*)&Y[(size_t)n * 128 + j0] = v;
        }
    }
}

// ---------------------------------------------------------------- gather-reduce conv
// one wave per destination node; lane L owns features [2L, 2L+1].
__global__ __launch_bounds__(256) void agg_gather(const float* __restrict__ Hin,
                                                  const int* __restrict__ srow,
                                                  const float* __restrict__ snorm,
                                                  const int* __restrict__ rs,
                                                  const float* __restrict__ bias,
                                                  float* __restrict__ Hout, int N) {
    int c = blockIdx.x * 4 + (threadIdx.x >> 6);
    if (c >= N) return;
    const int lane = threadIdx.x & 63;

    float2 acc;
    if (bias) { acc.x = bias[lane * 2]; acc.y = bias[lane * 2 + 1]; }
    else      { acc.x = 0.f; acc.y = 0.f; }

    int e    = rs[c];
    int eEnd = rs[c + 1];

    for (; e + 1 < eEnd; e += 2) {
        int   r0 = srow[e],  r1 = srow[e + 1];
        float n0 = snorm[e], n1 = snorm[e + 1];
        float2 v0 = *(const float2*)&Hin[(size_t)r0 * 128 + lane * 2];
        float2 v1 = *(const float2*)&Hin[(size_t)r1 * 128 + lane * 2];
        acc.x = fmaf(n0, v0.x, acc.x); acc.y = fmaf(n0, v0.y, acc.y);
        acc.x = fmaf(n1, v1.x, acc.x); acc.y = fmaf(n1, v1.y, acc.y);
    }
    if (e < eEnd) {
        int   r0 = srow[e];
        float n0 = snorm[e];
        float2 v0 = *(const float2*)&Hin[(size_t)r0 * 128 + lane * 2];
        acc.x = fmaf(n0, v0.x, acc.x); acc.y = fmaf(n0, v0.y, acc.y);
    }

    *(float2*)&Hout[(size_t)c * 128 + lane * 2] = acc;
}

// ---------------------------------------------------------------- batchnorm
__global__ __launch_bounds__(256) void bn_stats(const float* __restrict__ H,
                                                float* __restrict__ sums, int N) {
    int j = threadIdx.x & 127;
    float s = 0.f, s2 = 0.f;
    for (int n = blockIdx.x * 2 + (threadIdx.x >> 7); n < N; n += gridDim.x * 2) {
        float v = H[(size_t)n * 128 + j];
        s += v; s2 += v * v;
    }
    atomicAdd(&sums[j], s);
    atomicAdd(&sums[128 + j], s2);
}

__global__ __launch_bounds__(256) void bn_apply(const float* __restrict__ H,
                                                const float* __restrict__ sums,
                                                float* __restrict__ Y, int N, float invN) {
    int idx = blockIdx.x * blockDim.x + threadIdx.x;  // over N*32
    if (idx >= N * 32) return;
    int j0 = (idx & 31) * 4;
    float4 h = *(const float4*)&H[(size_t)idx * 4];
    float o[4];
    const float* hv = &h.x;
#pragma unroll
    for (int k = 0; k < 4; ++k) {
        float mu  = sums[j0 + k] * invN;
        float var = sums[128 + j0 + k] * invN - mu * mu;
        float v   = (hv[k] - mu) * rsqrtf(var + EPSF);
        o[k] = fmaxf(v, 0.f);
    }
    *(float4*)&Y[(size_t)idx * 4] = *(float4*)o;
}

// ---------------------------------------------------------------- launch
extern "C" void kernel_launch(void* const* d_in, const int* in_sizes, int n_in,
                              void* d_out, int out_size, void* d_ws, size_t ws_size,
                              hipStream_t stream) {
    const float* x  = (const float*)d_in[0];
    const int*   ei = (const int*)d_in[1];
    const float* ew = (const float*)d_in[2];
    const float* W0 = (const float*)d_in[3];
    const float* W1 = (const float*)d_in[5];
    const float* b1 = (const float*)d_in[6];

    const int N = in_sizes[0] / 128;
    const int E = in_sizes[2];
    const int* row = ei;
    const int* col = ei + E;

    // workspace carve-up (256B aligned)
    uintptr_t base = (uintptr_t)d_ws;
    auto alloc = [&](size_t bytes) {
        uintptr_t p = base;
        base += (bytes + 255) & ~(size_t)255;
        return (void*)p;
    };
    float* deg    = (float*)alloc((size_t)N * 4);        // becomes dinv in-place
    int*   cnt    = (int*)  alloc((size_t)N * 4);
    float* sums   = (float*)alloc(256 * 4);
    int*   rs     = (int*)  alloc((size_t)(N + 1) * 4);  // CSR row_start
    int*   cursor = (int*)  alloc((size_t)N * 4);
    int*   srow   = (int*)  alloc((size_t)E * 4);
    float* snorm  = (float*)alloc((size_t)E * 4);
    float* hA     = (float*)alloc((size_t)N * 128 * 4);
    float* out    = (float*)d_out;
    (void)ws_size; (void)n_in; (void)out_size;

    const float invN = 1.f / (float)N;

    // --- zero EXACT extents computed from allocator pointers.
    // (Round-2 bug: assumed packed layout; 256B alloc padding left the tail of
    //  `sums` un-zeroed -> bn_stats atomics accumulated across graph replays.)
    size_t degcnt_bytes = (size_t)((char*)cnt - (char*)deg) + (size_t)N * 4;
    hipMemsetAsync(deg, 0, degcnt_bytes, stream);     // deg + cnt (incl. padding)
    hipMemsetAsync(sums, 0, 256 * 4, stream);         // all 256 BN accumulators

    // --- CSR build: deg/hist -> dinv -> scan -> cursor copy -> scatter
    deg_hist_kernel<<<(E + 255) / 256, 256, 0, stream>>>(col, ew, deg, cnt, E);
    dinv_kernel<<<(N + 255) / 256, 256, 0, stream>>>(deg, N);
    scan_exclusive<<<1, 1024, 0, stream>>>(cnt, rs, N);
    hipMemcpyAsync(cursor, rs, (size_t)N * 4, hipMemcpyDeviceToDevice, stream);
    csr_scatter_kernel<<<(E + 255) / 256, 256, 0, stream>>>(row, col, ew, deg, cursor,
                                                            srow, snorm, E);

    // --- layer 0: hA = x @ W0^T
    gemm128<<<(N + 63) / 64, 512, 0, stream>>>(x, W0, hA, N);

    // --- conv 1: out = gather-reduce(hA)
    agg_gather<<<(N + 3) / 4, 256, 0, stream>>>(hA, srow, snorm, rs, nullptr, out, N);

    // --- batchnorm + relu: hA = relu(BN(out))   (b0 cancels inside BN)
    bn_stats<<<512, 256, 0, stream>>>(out, sums, N);
    bn_apply<<<(N * 32 + 255) / 256, 256, 0, stream>>>(out, sums, hA, N, invN);

    // --- layer 1: hA = hA @ W1^T (in-place safe)
    gemm128<<<(N + 63) / 64, 512, 0, stream>>>(hA, W1, hA, N);

    // --- conv 2 (+ b1 folded into accumulator init)
    agg_gather<<<(N + 3) / 4, 256, 0, stream>>>(hA, srow, snorm, rs, b1, out, N);
}

// Round 4
// 757.162 us; speedup vs baseline: 2.2368x; 1.1957x over previous
//
#include <hip/hip_runtime.h>
#include <cstdint>
#include <cstddef>

#define EPSF 1e-5f

// ---------------------------------------------------------------- deg + histogram (fused)
__global__ void deg_hist_kernel(const int* __restrict__ col, const float* __restrict__ w,
                                float* __restrict__ deg, int* __restrict__ cnt, int E) {
    int e = blockIdx.x * blockDim.x + threadIdx.x;
    if (e < E) {
        int c = col[e];
        atomicAdd(&deg[c], w[e]);
        atomicAdd(&cnt[c], 1);
    }
}

// in-place deg -> dinv
__global__ void dinv_kernel(float* __restrict__ deg, int N) {
    int i = blockIdx.x * blockDim.x + threadIdx.x;
    if (i < N) { float d = deg[i]; deg[i] = (d > 0.f) ? rsqrtf(d) : 0.f; }
}

// ---------------------------------------------------------------- 3-phase grid scan
// 4096 elements per block (1024 threads x int4). N=100K -> 25 blocks.
#define SCAN_ELEMS 4096

// Phase A: per-block total -> blockSums[b]
__global__ __launch_bounds__(1024) void scan_phaseA(const int* __restrict__ cnt,
                                                    int* __restrict__ blockSums, int N) {
    __shared__ int red[1024];
    const int t = threadIdx.x;
    const int base = blockIdx.x * SCAN_ELEMS + t * 4;
    int s = 0;
    if (base + 3 < N) {
        int4 v = *(const int4*)&cnt[base];
        s = v.x + v.y + v.z + v.w;
    } else {
#pragma unroll
        for (int i = 0; i < 4; ++i) if (base + i < N) s += cnt[base + i];
    }
    red[t] = s;
    __syncthreads();
    for (int off = 512; off > 0; off >>= 1) {
        if (t < off) red[t] += red[t + off];
        __syncthreads();
    }
    if (t == 0) blockSums[blockIdx.x] = red[0];
}

// Phase B: exclusive scan of blockSums in place (nb <= 1024, single block)
__global__ __launch_bounds__(1024) void scan_phaseB(int* __restrict__ blockSums, int nb) {
    __shared__ int part[1024];
    const int t = threadIdx.x;
    part[t] = (t < nb) ? blockSums[t] : 0;
    __syncthreads();
    for (int off = 1; off < 1024; off <<= 1) {
        int v = (t >= off) ? part[t - off] : 0;
        __syncthreads();
        part[t] += v;
        __syncthreads();
    }
    if (t < nb) blockSums[t] = (t == 0) ? 0 : part[t - 1];
}

// Phase C: full exclusive scan -> rs; rs[N] = E (total is known a priori)
__global__ __launch_bounds__(1024) void scan_phaseC(const int* __restrict__ cnt,
                                                    const int* __restrict__ blockSums,
                                                    int* __restrict__ rs, int N, int E) {
    __shared__ int part[1024];
    const int t = threadIdx.x;
    const int base = blockIdx.x * SCAN_ELEMS + t * 4;
    int v[4];
    if (base + 3 < N) {
        int4 q = *(const int4*)&cnt[base];
        v[0] = q.x; v[1] = q.y; v[2] = q.z; v[3] = q.w;
    } else {
#pragma unroll
        for (int i = 0; i < 4; ++i) v[i] = (base + i < N) ? cnt[base + i] : 0;
    }
    part[t] = v[0] + v[1] + v[2] + v[3];
    __syncthreads();
    for (int off = 1; off < 1024; off <<= 1) {
        int x = (t >= off) ? part[t - off] : 0;
        __syncthreads();
        part[t] += x;
        __syncthreads();
    }
    int run = blockSums[blockIdx.x] + ((t == 0) ? 0 : part[t - 1]);
    int o0 = run, o1 = run + v[0], o2 = o1 + v[1], o3 = o2 + v[2];
    if (base + 3 < N) {
        *(int4*)&rs[base] = make_int4(o0, o1, o2, o3);
    } else {
        int o[4] = {o0, o1, o2, o3};
#pragma unroll
        for (int i = 0; i < 4; ++i) if (base + i < N) rs[base + i] = o[i];
    }
    if (blockIdx.x == 0 && t == 0) rs[N] = E;
}

// ---------------------------------------------------------------- scatter edges into CSR slots
__global__ void csr_scatter_kernel(const int* __restrict__ row, const int* __restrict__ col,
                                   const float* __restrict__ w, const float* __restrict__ dinv,
                                   int* __restrict__ cursor,
                                   int* __restrict__ srow, float* __restrict__ snorm, int E) {
    int e = blockIdx.x * blockDim.x + threadIdx.x;
    if (e < E) {
        int r = row[e], c = col[e];
        int pos = atomicAdd(&cursor[c], 1);
        srow[pos]  = r;
        snorm[pos] = dinv[r] * dinv[c] * w[e];
    }
}

// ---------------------------------------------------------------- GEMM: Y = X @ W^T
// X [N,128], W [128,128] row-major. 64 rows/block, 512 threads, 4x4 register tile.
// Safe with Y == X (block stages its rows to LDS before writing).
__global__ __launch_bounds__(512) void gemm128(const float* __restrict__ X,
                                               const float* __restrict__ W,
                                               float* __restrict__ Y, int N) {
    __shared__ float WT[128][132];
    __shared__ float XT[128][68];

    const int t  = threadIdx.x;
    const int n0 = blockIdx.x * 64;

    for (int i = t; i < 128 * 128; i += 512) {
        int j = i >> 7, d = i & 127;
        WT[d][j] = W[i];
    }
    for (int i = t; i < 64 * 128; i += 512) {
        int nn = i >> 7, d = i & 127;
        int n = n0 + nn;
        XT[d][nn] = (n < N) ? X[(size_t)n * 128 + d] : 0.f;
    }
    __syncthreads();

    const int j0  = (t & 31) * 4;
    const int nn0 = (t >> 5) * 4;
    float acc[4][4] = {};

    for (int d = 0; d < 128; ++d) {
        float wv[4], xv[4];
        *(float4*)wv = *(const float4*)&WT[d][j0];
        *(float4*)xv = *(const float4*)&XT[d][nn0];
#pragma unroll
        for (int a = 0; a < 4; ++a)
#pragma unroll
            for (int b = 0; b < 4; ++b)
                acc[a][b] = fmaf(xv[a], wv[b], acc[a][b]);
    }

#pragma unroll
    for (int a = 0; a < 4; ++a) {
        int n = n0 + nn0 + a;
        if (n < N) {
            float4 v = make_float4(acc[a][0], acc[a][1], acc[a][2], acc[a][3]);
            *(float4*)&Y[(size_t)n * 128 + j0] = v;
        }
    }
}

// ---------------------------------------------------------------- gather-reduce conv
// one wave per destination node; lane L owns features [2L, 2L+1].
__global__ __launch_bounds__(256) void agg_gather(const float* __restrict__ Hin,
                                                  const int* __restrict__ srow,
                                                  const float* __restrict__ snorm,
                                                  const int* __restrict__ rs,
                                                  const float* __restrict__ bias,
                                                  float* __restrict__ Hout, int N) {
    int c = blockIdx.x * 4 + (threadIdx.x >> 6);
    if (c >= N) return;
    const int lane = threadIdx.x & 63;

    float2 acc;
    if (bias) { acc.x = bias[lane * 2]; acc.y = bias[lane * 2 + 1]; }
    else      { acc.x = 0.f; acc.y = 0.f; }

    int e    = rs[c];
    int eEnd = rs[c + 1];

    for (; e + 1 < eEnd; e += 2) {
        int   r0 = srow[e],  r1 = srow[e + 1];
        float n0 = snorm[e], n1 = snorm[e + 1];
        float2 v0 = *(const float2*)&Hin[(size_t)r0 * 128 + lane * 2];
        float2 v1 = *(const float2*)&Hin[(size_t)r1 * 128 + lane * 2];
        acc.x = fmaf(n0, v0.x, acc.x); acc.y = fmaf(n0, v0.y, acc.y);
        acc.x = fmaf(n1, v1.x, acc.x); acc.y = fmaf(n1, v1.y, acc.y);
    }
    if (e < eEnd) {
        int   r0 = srow[e];
        float n0 = snorm[e];
        float2 v0 = *(const float2*)&Hin[(size_t)r0 * 128 + lane * 2];
        acc.x = fmaf(n0, v0.x, acc.x); acc.y = fmaf(n0, v0.y, acc.y);
    }

    *(float2*)&Hout[(size_t)c * 128 + lane * 2] = acc;
}

// ---------------------------------------------------------------- batchnorm
__global__ __launch_bounds__(256) void bn_stats(const float* __restrict__ H,
                                                float* __restrict__ sums, int N) {
    int j = threadIdx.x & 127;
    float s = 0.f, s2 = 0.f;
    for (int n = blockIdx.x * 2 + (threadIdx.x >> 7); n < N; n += gridDim.x * 2) {
        float v = H[(size_t)n * 128 + j];
        s += v; s2 += v * v;
    }
    atomicAdd(&sums[j], s);
    atomicAdd(&sums[128 + j], s2);
}

__global__ __launch_bounds__(256) void bn_apply(const float* __restrict__ H,
                                                const float* __restrict__ sums,
                                                float* __restrict__ Y, int N, float invN) {
    int idx = blockIdx.x * blockDim.x + threadIdx.x;  // over N*32
    if (idx >= N * 32) return;
    int j0 = (idx & 31) * 4;
    float4 h = *(const float4*)&H[(size_t)idx * 4];
    float o[4];
    const float* hv = &h.x;
#pragma unroll
    for (int k = 0; k < 4; ++k) {
        float mu  = sums[j0 + k] * invN;
        float var = sums[128 + j0 + k] * invN - mu * mu;
        float v   = (hv[k] - mu) * rsqrtf(var + EPSF);
        o[k] = fmaxf(v, 0.f);
    }
    *(float4*)&Y[(size_t)idx * 4] = *(float4*)o;
}

// ---------------------------------------------------------------- launch
extern "C" void kernel_launch(void* const* d_in, const int* in_sizes, int n_in,
                              void* d_out, int out_size, void* d_ws, size_t ws_size,
                              hipStream_t stream) {
    const float* x  = (const float*)d_in[0];
    const int*   ei = (const int*)d_in[1];
    const float* ew = (const float*)d_in[2];
    const float* W0 = (const float*)d_in[3];
    const float* W1 = (const float*)d_in[5];
    const float* b1 = (const float*)d_in[6];

    const int N = in_sizes[0] / 128;
    const int E = in_sizes[2];
    const int* row = ei;
    const int* col = ei + E;

    // workspace carve-up (256B aligned)
    uintptr_t base = (uintptr_t)d_ws;
    auto alloc = [&](size_t bytes) {
        uintptr_t p = base;
        base += (bytes + 255) & ~(size_t)255;
        return (void*)p;
    };
    float* deg    = (float*)alloc((size_t)N * 4);        // becomes dinv in-place
    int*   cnt    = (int*)  alloc((size_t)N * 4);
    float* sums   = (float*)alloc(256 * 4);
    int*   bsums  = (int*)  alloc(1024 * 4);             // scan block partials
    int*   rs     = (int*)  alloc((size_t)(N + 1) * 4);  // CSR row_start
    int*   cursor = (int*)  alloc((size_t)N * 4);
    int*   srow   = (int*)  alloc((size_t)E * 4);
    float* snorm  = (float*)alloc((size_t)E * 4);
    float* hA     = (float*)alloc((size_t)N * 128 * 4);
    float* out    = (float*)d_out;
    (void)ws_size; (void)n_in; (void)out_size;

    const float invN = 1.f / (float)N;
    const int nScanBlocks = (N + SCAN_ELEMS - 1) / SCAN_ELEMS;  // 25 for N=100K

    // --- zero EXACT extents computed from allocator pointers
    size_t degcnt_bytes = (size_t)((char*)cnt - (char*)deg) + (size_t)N * 4;
    hipMemsetAsync(deg, 0, degcnt_bytes, stream);     // deg + cnt
    hipMemsetAsync(sums, 0, 256 * 4, stream);         // BN accumulators

    // --- CSR build: deg/hist -> dinv -> 3-phase scan -> cursor copy -> scatter
    deg_hist_kernel<<<(E + 255) / 256, 256, 0, stream>>>(col, ew, deg, cnt, E);
    dinv_kernel<<<(N + 255) / 256, 256, 0, stream>>>(deg, N);
    scan_phaseA<<<nScanBlocks, 1024, 0, stream>>>(cnt, bsums, N);
    scan_phaseB<<<1, 1024, 0, stream>>>(bsums, nScanBlocks);
    scan_phaseC<<<nScanBlocks, 1024, 0, stream>>>(cnt, bsums, rs, N, E);
    hipMemcpyAsync(cursor, rs, (size_t)N * 4, hipMemcpyDeviceToDevice, stream);
    csr_scatter_kernel<<<(E + 255) / 256, 256, 0, stream>>>(row, col, ew, deg, cursor,
                                                            srow, snorm, E);

    // --- layer 0: hA = x @ W0^T
    gemm128<<<(N + 63) / 64, 512, 0, stream>>>(x, W0, hA, N);

    // --- conv 1: out = gather-reduce(hA)
    agg_gather<<<(N + 3) / 4, 256, 0, stream>>>(hA, srow, snorm, rs, nullptr, out, N);

    // --- batchnorm + relu: hA = relu(BN(out))   (b0 cancels inside BN)
    bn_stats<<<512, 256, 0, stream>>>(out, sums, N);
    bn_apply<<<(N * 32 + 255) / 256, 256, 0, stream>>>(out, sums, hA, N, invN);

    // --- layer 1: hA = hA @ W1^T (in-place safe)
    gemm128<<<(N + 63) / 64, 512, 0, stream>>>(hA, W1, hA, N);

    // --- conv 2 (+ b1 folded into accumulator init)
    agg_gather<<<(N + 3) / 4, 256, 0, stream>>>(hA, srow, snorm, rs, b1, out, N);
}

// Round 5
// 522.519 us; speedup vs baseline: 3.2413x; 1.4491x over previous
//
#include <hip/hip_runtime.h>
#include <cstdint>
#include <cstddef>

#define EPSF 1e-5f

typedef unsigned long long ull;
typedef __attribute__((ext_vector_type(8))) short bf16x8;
typedef __attribute__((ext_vector_type(4))) float f32x4;

// ---------------------------------------------------------------- packed deg+cnt histogram
// one u64 atomic per edge: high 20 bits = count, low 44 bits = deg in 2^-32 fixed point.
// max in-degree ~60 -> deg < 2^44 (no carry into cnt); integer add = order-independent.
__global__ void deg_hist_kernel(const int* __restrict__ col, const float* __restrict__ w,
                                ull* __restrict__ dc, int E) {
    int e = blockIdx.x * blockDim.x + threadIdx.x;
    if (e < E) {
        ull add = (1ULL << 44) | (ull)(w[e] * 4294967296.0f);
        atomicAdd(&dc[col[e]], add);
    }
}

// unpack: dinv[i] = rsqrt(deg), cnt[i] = count
__global__ void dc_finalize(const ull* __restrict__ dc, float* __restrict__ dinv,
                            int* __restrict__ cnt, int N) {
    int i = blockIdx.x * blockDim.x + threadIdx.x;
    if (i < N) {
        ull v = dc[i];
        float d = (float)(v & 0xFFFFFFFFFFFULL) * 2.3283064365386963e-10f;  // * 2^-32
        dinv[i] = (d > 0.f) ? rsqrtf(d) : 0.f;
        cnt[i]  = (int)(v >> 44);
    }
}

// ---------------------------------------------------------------- 3-phase grid scan
#define SCAN_ELEMS 4096

__global__ __launch_bounds__(1024) void scan_phaseA(const int* __restrict__ cnt,
                                                    int* __restrict__ blockSums, int N) {
    __shared__ int red[1024];
    const int t = threadIdx.x;
    const int base = blockIdx.x * SCAN_ELEMS + t * 4;
    int s = 0;
    if (base + 3 < N) {
        int4 v = *(const int4*)&cnt[base];
        s = v.x + v.y + v.z + v.w;
    } else {
#pragma unroll
        for (int i = 0; i < 4; ++i) if (base + i < N) s += cnt[base + i];
    }
    red[t] = s;
    __syncthreads();
    for (int off = 512; off > 0; off >>= 1) {
        if (t < off) red[t] += red[t + off];
        __syncthreads();
    }
    if (t == 0) blockSums[blockIdx.x] = red[0];
}

__global__ __launch_bounds__(1024) void scan_phaseB(int* __restrict__ blockSums, int nb) {
    __shared__ int part[1024];
    const int t = threadIdx.x;
    part[t] = (t < nb) ? blockSums[t] : 0;
    __syncthreads();
    for (int off = 1; off < 1024; off <<= 1) {
        int v = (t >= off) ? part[t - off] : 0;
        __syncthreads();
        part[t] += v;
        __syncthreads();
    }
    if (t < nb) blockSums[t] = (t == 0) ? 0 : part[t - 1];
}

__global__ __launch_bounds__(1024) void scan_phaseC(const int* __restrict__ cnt,
                                                    const int* __restrict__ blockSums,
                                                    int* __restrict__ rs, int N, int E) {
    __shared__ int part[1024];
    const int t = threadIdx.x;
    const int base = blockIdx.x * SCAN_ELEMS + t * 4;
    int v[4];
    if (base + 3 < N) {
        int4 q = *(const int4*)&cnt[base];
        v[0] = q.x; v[1] = q.y; v[2] = q.z; v[3] = q.w;
    } else {
#pragma unroll
        for (int i = 0; i < 4; ++i) v[i] = (base + i < N) ? cnt[base + i] : 0;
    }
    part[t] = v[0] + v[1] + v[2] + v[3];
    __syncthreads();
    for (int off = 1; off < 1024; off <<= 1) {
        int x = (t >= off) ? part[t - off] : 0;
        __syncthreads();
        part[t] += x;
        __syncthreads();
    }
    int run = blockSums[blockIdx.x] + ((t == 0) ? 0 : part[t - 1]);
    int o0 = run, o1 = run + v[0], o2 = o1 + v[1], o3 = o2 + v[2];
    if (base + 3 < N) {
        *(int4*)&rs[base] = make_int4(o0, o1, o2, o3);
    } else {
        int o[4] = {o0, o1, o2, o3};
#pragma unroll
        for (int i = 0; i < 4; ++i) if (base + i < N) rs[base + i] = o[i];
    }
    if (blockIdx.x == 0 && t == 0) rs[N] = E;
}

// ---------------------------------------------------------------- scatter edges into CSR
// packed record: sedge[pos] = {srow, bits(norm)} -> one 8B scattered write per edge
__global__ void csr_scatter_kernel(const int* __restrict__ row, const int* __restrict__ col,
                                   const float* __restrict__ w, const float* __restrict__ dinv,
                                   int* __restrict__ cursor, int2* __restrict__ sedge, int E) {
    int e = blockIdx.x * blockDim.x + threadIdx.x;
    if (e < E) {
        int r = row[e], c = col[e];
        int pos = atomicAdd(&cursor[c], 1);
        sedge[pos] = make_int2(r, __float_as_int(dinv[r] * dinv[c] * w[e]));
    }
}

// ---------------------------------------------------------------- bf16 MFMA GEMM: Y = X @ W^T
// X [N,128] f32, W [128,128] f32 row-major. Block = 256 thr (4 waves), 64 rows.
// LDS bf16 with XOR swizzle (k ^= (row&7)<<3) -> 2-way (free) instead of 16-way conflicts.
// f32 accumulate. In-place safe (block stages its own rows before writing).
__device__ __forceinline__ ushort f2bf(float f) {
    uint b = __float_as_uint(f);
    return (ushort)((b + 0x7FFFu + ((b >> 16) & 1u)) >> 16);  // RNE
}
__device__ __forceinline__ uint4 pack8(const float* f) {
    uint4 o;
    o.x = f2bf(f[0]) | ((uint)f2bf(f[1]) << 16);
    o.y = f2bf(f[2]) | ((uint)f2bf(f[3]) << 16);
    o.z = f2bf(f[4]) | ((uint)f2bf(f[5]) << 16);
    o.w = f2bf(f[6]) | ((uint)f2bf(f[7]) << 16);
    return o;
}

__global__ __launch_bounds__(256) void gemm128_mfma(const float* __restrict__ X,
                                                    const float* __restrict__ W,
                                                    float* __restrict__ Y, int N) {
    __shared__ __align__(16) ushort Alds[64][128];   // 16 KB
    __shared__ __align__(16) ushort Blds[128][128];  // 32 KB

    const int t  = threadIdx.x;
    const int n0 = blockIdx.x * 64;

    // stage W: Blds[j][k^swz] = bf16(W[j][k])
    for (int i = t; i < 128 * 16; i += 256) {
        int j = i >> 4, kc = (i & 15) << 3;
        float f[8];
        *(float4*)&f[0] = *(const float4*)&W[j * 128 + kc];
        *(float4*)&f[4] = *(const float4*)&W[j * 128 + kc + 4];
        *(uint4*)&Blds[j][kc ^ ((j & 7) << 3)] = pack8(f);
    }
    // stage X rows n0..n0+63
    for (int i = t; i < 64 * 16; i += 256) {
        int r = i >> 4, kc = (i & 15) << 3;
        int n = n0 + r;
        float f[8] = {0.f, 0.f, 0.f, 0.f, 0.f, 0.f, 0.f, 0.f};
        if (n < N) {
            *(float4*)&f[0] = *(const float4*)&X[(size_t)n * 128 + kc];
            *(float4*)&f[4] = *(const float4*)&X[(size_t)n * 128 + kc + 4];
        }
        *(uint4*)&Alds[r][kc ^ ((r & 7) << 3)] = pack8(f);
    }
    __syncthreads();

    const int lane  = t & 63;
    const int wv    = t >> 6;
    const int arow  = wv * 16 + (lane & 15);           // A row within tile
    const int klane = (lane >> 4) << 3;                // k sub-offset 0/8/16/24
    const int cq    = lane & 15;                       // C/D col

    f32x4 acc[8] = {};

    for (int ks = 0; ks < 4; ++ks) {
        const int k0 = ks * 32 + klane;
        bf16x8 a = *(const bf16x8*)&Alds[arow][k0 ^ ((arow & 7) << 3)];
#pragma unroll
        for (int tl = 0; tl < 8; ++tl) {
            int colr = tl * 16 + cq;
            bf16x8 b = *(const bf16x8*)&Blds[colr][k0 ^ ((colr & 7) << 3)];
            acc[tl] = __builtin_amdgcn_mfma_f32_16x16x32_bf16(a, b, acc[tl], 0, 0, 0);
        }
    }

    // C/D: col = lane&15, row = (lane>>4)*4 + reg   [m89-verified layout]
    const int r0 = n0 + wv * 16 + ((lane >> 4) << 2);
#pragma unroll
    for (int tl = 0; tl < 8; ++tl) {
#pragma unroll
        for (int reg = 0; reg < 4; ++reg) {
            int rr = r0 + reg;
            if (rr < N) Y[(size_t)rr * 128 + tl * 16 + cq] = acc[tl][reg];
        }
    }
}

// ---------------------------------------------------------------- gather-reduce conv
// one wave per destination node; lane L owns features [2L, 2L+1].
__global__ __launch_bounds__(256) void agg_gather(const float* __restrict__ Hin,
                                                  const int2* __restrict__ sedge,
                                                  const int* __restrict__ rs,
                                                  const float* __restrict__ bias,
                                                  float* __restrict__ Hout, int N) {
    int c = blockIdx.x * 4 + (threadIdx.x >> 6);
    if (c >= N) return;
    const int lane = threadIdx.x & 63;

    float2 acc;
    if (bias) { acc.x = bias[lane * 2]; acc.y = bias[lane * 2 + 1]; }
    else      { acc.x = 0.f; acc.y = 0.f; }

    int e    = rs[c];
    int eEnd = rs[c + 1];

    for (; e + 1 < eEnd; e += 2) {
        int2 s0 = sedge[e], s1 = sedge[e + 1];
        float n0 = __int_as_float(s0.y), n1 = __int_as_float(s1.y);
        float2 v0 = *(const float2*)&Hin[(size_t)s0.x * 128 + lane * 2];
        float2 v1 = *(const float2*)&Hin[(size_t)s1.x * 128 + lane * 2];
        acc.x = fmaf(n0, v0.x, acc.x); acc.y = fmaf(n0, v0.y, acc.y);
        acc.x = fmaf(n1, v1.x, acc.x); acc.y = fmaf(n1, v1.y, acc.y);
    }
    if (e < eEnd) {
        int2 s0 = sedge[e];
        float n0 = __int_as_float(s0.y);
        float2 v0 = *(const float2*)&Hin[(size_t)s0.x * 128 + lane * 2];
        acc.x = fmaf(n0, v0.x, acc.x); acc.y = fmaf(n0, v0.y, acc.y);
    }

    *(float2*)&Hout[(size_t)c * 128 + lane * 2] = acc;
}

// ---------------------------------------------------------------- batchnorm
__global__ __launch_bounds__(256) void bn_stats(const float* __restrict__ H,
                                                float* __restrict__ sums, int N) {
    int j = threadIdx.x & 127;
    float s = 0.f, s2 = 0.f;
    for (int n = blockIdx.x * 2 + (threadIdx.x >> 7); n < N; n += gridDim.x * 2) {
        float v = H[(size_t)n * 128 + j];
        s += v; s2 += v * v;
    }
    atomicAdd(&sums[j], s);
    atomicAdd(&sums[128 + j], s2);
}

__global__ __launch_bounds__(256) void bn_apply(const float* __restrict__ H,
                                                const float* __restrict__ sums,
                                                float* __restrict__ Y, int N, float invN) {
    int idx = blockIdx.x * blockDim.x + threadIdx.x;  // over N*32
    if (idx >= N * 32) return;
    int j0 = (idx & 31) * 4;
    float4 h = *(const float4*)&H[(size_t)idx * 4];
    float o[4];
    const float* hv = &h.x;
#pragma unroll
    for (int k = 0; k < 4; ++k) {
        float mu  = sums[j0 + k] * invN;
        float var = sums[128 + j0 + k] * invN - mu * mu;
        float v   = (hv[k] - mu) * rsqrtf(var + EPSF);
        o[k] = fmaxf(v, 0.f);
    }
    *(float4*)&Y[(size_t)idx * 4] = *(float4*)o;
}

// ---------------------------------------------------------------- launch
extern "C" void kernel_launch(void* const* d_in, const int* in_sizes, int n_in,
                              void* d_out, int out_size, void* d_ws, size_t ws_size,
                              hipStream_t stream) {
    const float* x  = (const float*)d_in[0];
    const int*   ei = (const int*)d_in[1];
    const float* ew = (const float*)d_in[2];
    const float* W0 = (const float*)d_in[3];
    const float* W1 = (const float*)d_in[5];
    const float* b1 = (const float*)d_in[6];

    const int N = in_sizes[0] / 128;
    const int E = in_sizes[2];
    const int* row = ei;
    const int* col = ei + E;

    // workspace carve-up (256B aligned)
    uintptr_t base = (uintptr_t)d_ws;
    auto alloc = [&](size_t bytes) {
        uintptr_t p = base;
        base += (bytes + 255) & ~(size_t)255;
        return (void*)p;
    };
    ull*   dc     = (ull*)  alloc((size_t)N * 8);        // packed deg|cnt
    float* dinv   = (float*)alloc((size_t)N * 4);
    int*   cnt    = (int*)  alloc((size_t)N * 4);
    float* sums   = (float*)alloc(256 * 4);
    int*   bsums  = (int*)  alloc(1024 * 4);
    int*   rs     = (int*)  alloc((size_t)(N + 1) * 4);
    int*   cursor = (int*)  alloc((size_t)N * 4);
    int2*  sedge  = (int2*) alloc((size_t)E * 8);        // packed {row, norm}
    float* hA     = (float*)alloc((size_t)N * 128 * 4);
    float* out    = (float*)d_out;
    (void)ws_size; (void)n_in; (void)out_size;

    const float invN = 1.f / (float)N;
    const int nScanBlocks = (N + SCAN_ELEMS - 1) / SCAN_ELEMS;  // 25 for N=100K

    // --- per-call zeroing (harness does not re-poison between replays)
    hipMemsetAsync(dc, 0, (size_t)N * 8, stream);
    hipMemsetAsync(sums, 0, 256 * 4, stream);

    // --- CSR build
    deg_hist_kernel<<<(E + 255) / 256, 256, 0, stream>>>(col, ew, dc, E);
    dc_finalize<<<(N + 255) / 256, 256, 0, stream>>>(dc, dinv, cnt, N);
    scan_phaseA<<<nScanBlocks, 1024, 0, stream>>>(cnt, bsums, N);
    scan_phaseB<<<1, 1024, 0, stream>>>(bsums, nScanBlocks);
    scan_phaseC<<<nScanBlocks, 1024, 0, stream>>>(cnt, bsums, rs, N, E);
    hipMemcpyAsync(cursor, rs, (size_t)N * 4, hipMemcpyDeviceToDevice, stream);
    csr_scatter_kernel<<<(E + 255) / 256, 256, 0, stream>>>(row, col, ew, dinv, cursor,
                                                            sedge, E);

    // --- layer 0: hA = x @ W0^T  (bf16 MFMA)
    gemm128_mfma<<<(N + 63) / 64, 256, 0, stream>>>(x, W0, hA, N);

    // --- conv 1: out = gather-reduce(hA)
    agg_gather<<<(N + 3) / 4, 256, 0, stream>>>(hA, sedge, rs, nullptr, out, N);

    // --- batchnorm + relu: hA = relu(BN(out))   (b0 cancels inside BN)
    bn_stats<<<512, 256, 0, stream>>>(out, sums, N);
    bn_apply<<<(N * 32 + 255) / 256, 256, 0, stream>>>(out, sums, hA, N, invN);

    // --- layer 1: hA = hA @ W1^T (bf16 MFMA, in-place safe)
    gemm128_mfma<<<(N + 63) / 64, 256, 0, stream>>>(hA, W1, hA, N);

    // --- conv 2 (+ b1 folded into accumulator init)
    agg_gather<<<(N + 3) / 4, 256, 0, stream>>>(hA, sedge, rs, b1, out, N);
}

// Round 6
// 420.078 us; speedup vs baseline: 4.0318x; 1.2439x over previous
//
#include <hip/hip_runtime.h>
#include <cstdint>
#include <cstddef>

#define EPSF 1e-5f

typedef unsigned long long ull;
typedef __attribute__((ext_vector_type(8))) short bf16x8;
typedef __attribute__((ext_vector_type(4))) float f32x4;

// ---------------------------------------------------------------- packed deg+cnt histogram
// one u64 atomic per edge: high 20 bits = count, low 44 bits = deg in 2^-32 fixed point.
// max in-degree ~60 -> deg < 2^44 (no carry into cnt); integer add = order-independent.
__global__ void deg_hist_kernel(const int* __restrict__ col, const float* __restrict__ w,
                                ull* __restrict__ dc, int E) {
    int e = blockIdx.x * blockDim.x + threadIdx.x;
    if (e < E) {
        ull add = (1ULL << 44) | (ull)(w[e] * 4294967296.0f);
        atomicAdd(&dc[col[e]], add);
    }
}

// unpack: dinv[i] = rsqrt(deg), cnt[i] = count
__global__ void dc_finalize(const ull* __restrict__ dc, float* __restrict__ dinv,
                            int* __restrict__ cnt, int N) {
    int i = blockIdx.x * blockDim.x + threadIdx.x;
    if (i < N) {
        ull v = dc[i];
        float d = (float)(v & 0xFFFFFFFFFFFULL) * 2.3283064365386963e-10f;  // * 2^-32
        dinv[i] = (d > 0.f) ? rsqrtf(d) : 0.f;
        cnt[i]  = (int)(v >> 44);
    }
}

// ---------------------------------------------------------------- 3-phase grid scan
#define SCAN_ELEMS 4096

__global__ __launch_bounds__(1024) void scan_phaseA(const int* __restrict__ cnt,
                                                    int* __restrict__ blockSums, int N) {
    __shared__ int red[1024];
    const int t = threadIdx.x;
    const int base = blockIdx.x * SCAN_ELEMS + t * 4;
    int s = 0;
    if (base + 3 < N) {
        int4 v = *(const int4*)&cnt[base];
        s = v.x + v.y + v.z + v.w;
    } else {
#pragma unroll
        for (int i = 0; i < 4; ++i) if (base + i < N) s += cnt[base + i];
    }
    red[t] = s;
    __syncthreads();
    for (int off = 512; off > 0; off >>= 1) {
        if (t < off) red[t] += red[t + off];
        __syncthreads();
    }
    if (t == 0) blockSums[blockIdx.x] = red[0];
}

__global__ __launch_bounds__(1024) void scan_phaseB(int* __restrict__ blockSums, int nb) {
    __shared__ int part[1024];
    const int t = threadIdx.x;
    part[t] = (t < nb) ? blockSums[t] : 0;
    __syncthreads();
    for (int off = 1; off < 1024; off <<= 1) {
        int v = (t >= off) ? part[t - off] : 0;
        __syncthreads();
        part[t] += v;
        __syncthreads();
    }
    if (t < nb) blockSums[t] = (t == 0) ? 0 : part[t - 1];
}

// Phase C: exclusive scan -> rs AND cursor (saves a d2d copy); rs[N] = E
__global__ __launch_bounds__(1024) void scan_phaseC(const int* __restrict__ cnt,
                                                    const int* __restrict__ blockSums,
                                                    int* __restrict__ rs,
                                                    int* __restrict__ cursor, int N, int E) {
    __shared__ int part[1024];
    const int t = threadIdx.x;
    const int base = blockIdx.x * SCAN_ELEMS + t * 4;
    int v[4];
    if (base + 3 < N) {
        int4 q = *(const int4*)&cnt[base];
        v[0] = q.x; v[1] = q.y; v[2] = q.z; v[3] = q.w;
    } else {
#pragma unroll
        for (int i = 0; i < 4; ++i) v[i] = (base + i < N) ? cnt[base + i] : 0;
    }
    part[t] = v[0] + v[1] + v[2] + v[3];
    __syncthreads();
    for (int off = 1; off < 1024; off <<= 1) {
        int x = (t >= off) ? part[t - off] : 0;
        __syncthreads();
        part[t] += x;
        __syncthreads();
    }
    int run = blockSums[blockIdx.x] + ((t == 0) ? 0 : part[t - 1]);
    int o0 = run, o1 = run + v[0], o2 = o1 + v[1], o3 = o2 + v[2];
    if (base + 3 < N) {
        int4 o = make_int4(o0, o1, o2, o3);
        *(int4*)&rs[base] = o;
        *(int4*)&cursor[base] = o;
    } else {
        int o[4] = {o0, o1, o2, o3};
#pragma unroll
        for (int i = 0; i < 4; ++i) if (base + i < N) { rs[base + i] = o[i]; cursor[base + i] = o[i]; }
    }
    if (blockIdx.x == 0 && t == 0) rs[N] = E;
}

// ---------------------------------------------------------------- scatter edges into CSR
// packed record: sedge[pos] = {srow, bits(norm)} -> one 8B scattered write per edge
__global__ void csr_scatter_kernel(const int* __restrict__ row, const int* __restrict__ col,
                                   const float* __restrict__ w, const float* __restrict__ dinv,
                                   int* __restrict__ cursor, int2* __restrict__ sedge, int E) {
    int e = blockIdx.x * blockDim.x + threadIdx.x;
    if (e < E) {
        int r = row[e], c = col[e];
        int pos = atomicAdd(&cursor[c], 1);
        sedge[pos] = make_int2(r, __float_as_int(dinv[r] * dinv[c] * w[e]));
    }
}

// ---------------------------------------------------------------- bf16 MFMA GEMM: Y = X @ W^T
// X [N,128] (f32 or bf16), W [128,128] f32 row-major, Y [N,128] bf16.
// Block = 256 thr (4 waves), 64 rows. LDS bf16, XOR swizzle (k ^= (row&7)<<3).
__device__ __forceinline__ ushort f2bf(float f) {
    uint b = __float_as_uint(f);
    return (ushort)((b + 0x7FFFu + ((b >> 16) & 1u)) >> 16);  // RNE
}
__device__ __forceinline__ uint4 pack8(const float* f) {
    uint4 o;
    o.x = f2bf(f[0]) | ((uint)f2bf(f[1]) << 16);
    o.y = f2bf(f[2]) | ((uint)f2bf(f[3]) << 16);
    o.z = f2bf(f[4]) | ((uint)f2bf(f[5]) << 16);
    o.w = f2bf(f[6]) | ((uint)f2bf(f[7]) << 16);
    return o;
}

template <bool IN_BF16>
__global__ __launch_bounds__(256) void gemm128_mfma(const void* __restrict__ Xv,
                                                    const float* __restrict__ W,
                                                    ushort* __restrict__ Y, int N) {
    __shared__ __align__(16) ushort Alds[64][128];   // 16 KB
    __shared__ __align__(16) ushort Blds[128][128];  // 32 KB

    const int t  = threadIdx.x;
    const int n0 = blockIdx.x * 64;

    // stage W: Blds[j][k^swz] = bf16(W[j][k])
    for (int i = t; i < 128 * 16; i += 256) {
        int j = i >> 4, kc = (i & 15) << 3;
        float f[8];
        *(float4*)&f[0] = *(const float4*)&W[j * 128 + kc];
        *(float4*)&f[4] = *(const float4*)&W[j * 128 + kc + 4];
        *(uint4*)&Blds[j][kc ^ ((j & 7) << 3)] = pack8(f);
    }
    // stage X rows n0..n0+63
    for (int i = t; i < 64 * 16; i += 256) {
        int r = i >> 4, kc = (i & 15) << 3;
        int n = n0 + r;
        uint4 v = make_uint4(0u, 0u, 0u, 0u);
        if (n < N) {
            if constexpr (IN_BF16) {
                v = *(const uint4*)&((const ushort*)Xv)[(size_t)n * 128 + kc];
            } else {
                float f[8];
                *(float4*)&f[0] = *(const float4*)&((const float*)Xv)[(size_t)n * 128 + kc];
                *(float4*)&f[4] = *(const float4*)&((const float*)Xv)[(size_t)n * 128 + kc + 4];
                v = pack8(f);
            }
        }
        *(uint4*)&Alds[r][kc ^ ((r & 7) << 3)] = v;
    }
    __syncthreads();

    const int lane  = t & 63;
    const int wv    = t >> 6;
    const int arow  = wv * 16 + (lane & 15);
    const int klane = (lane >> 4) << 3;
    const int cq    = lane & 15;

    f32x4 acc[8] = {};

    for (int ks = 0; ks < 4; ++ks) {
        const int k0 = ks * 32 + klane;
        bf16x8 a = *(const bf16x8*)&Alds[arow][k0 ^ ((arow & 7) << 3)];
#pragma unroll
        for (int tl = 0; tl < 8; ++tl) {
            int colr = tl * 16 + cq;
            bf16x8 b = *(const bf16x8*)&Blds[colr][k0 ^ ((colr & 7) << 3)];
            acc[tl] = __builtin_amdgcn_mfma_f32_16x16x32_bf16(a, b, acc[tl], 0, 0, 0);
        }
    }

    // C/D: col = lane&15, row = (lane>>4)*4 + reg   [m89-verified layout]
    const int r0 = n0 + wv * 16 + ((lane >> 4) << 2);
#pragma unroll
    for (int tl = 0; tl < 8; ++tl) {
#pragma unroll
        for (int reg = 0; reg < 4; ++reg) {
            int rr = r0 + reg;
            if (rr < N) Y[(size_t)rr * 128 + tl * 16 + cq] = f2bf(acc[tl][reg]);
        }
    }
}

// ---------------------------------------------------------------- gather-reduce conv (bf16 src)
// one wave per destination node; lane L owns features [2L, 2L+1] (one u32 = 2 bf16).
__global__ __launch_bounds__(256) void agg_gather(const ushort* __restrict__ Hin,
                                                  const int2* __restrict__ sedge,
                                                  const int* __restrict__ rs,
                                                  const float* __restrict__ bias,
                                                  float* __restrict__ Hout, int N) {
    int c = blockIdx.x * 4 + (threadIdx.x >> 6);
    if (c >= N) return;
    const int lane = threadIdx.x & 63;

    float2 acc;
    if (bias) { acc.x = bias[lane * 2]; acc.y = bias[lane * 2 + 1]; }
    else      { acc.x = 0.f; acc.y = 0.f; }

    int e    = rs[c];
    int eEnd = rs[c + 1];

#define GLOAD(s, nv, vv)                                                       \
    float nv = __int_as_float((s).y);                                         \
    uint  vv = *(const uint*)&Hin[(size_t)(s).x * 128 + lane * 2];

#define GACC(nv, vv)                                                           \
    acc.x = fmaf(nv, __uint_as_float((vv) << 16), acc.x);                      \
    acc.y = fmaf(nv, __uint_as_float((vv) & 0xFFFF0000u), acc.y);

    for (; e + 3 < eEnd; e += 4) {
        int2 s0 = sedge[e], s1 = sedge[e + 1], s2 = sedge[e + 2], s3 = sedge[e + 3];
        GLOAD(s0, n0, v0) GLOAD(s1, n1, v1) GLOAD(s2, n2, v2) GLOAD(s3, n3, v3)
        GACC(n0, v0) GACC(n1, v1) GACC(n2, v2) GACC(n3, v3)
    }
    for (; e < eEnd; ++e) {
        int2 s0 = sedge[e];
        GLOAD(s0, n0, v0)
        GACC(n0, v0)
    }
#undef GLOAD
#undef GACC

    *(float2*)&Hout[(size_t)c * 128 + lane * 2] = acc;
}

// ---------------------------------------------------------------- batchnorm
__global__ __launch_bounds__(256) void bn_stats(const float* __restrict__ H,
                                                float* __restrict__ sums, int N) {
    int j = threadIdx.x & 127;
    float s = 0.f, s2 = 0.f;
    for (int n = blockIdx.x * 2 + (threadIdx.x >> 7); n < N; n += gridDim.x * 2) {
        float v = H[(size_t)n * 128 + j];
        s += v; s2 += v * v;
    }
    atomicAdd(&sums[j], s);
    atomicAdd(&sums[128 + j], s2);
}

// Y(bf16) = relu((H - mu) * rsqrt(var + eps)); feeds GEMM1 which stages bf16 anyway
__global__ __launch_bounds__(256) void bn_apply(const float* __restrict__ H,
                                                const float* __restrict__ sums,
                                                ushort* __restrict__ Y, int N, float invN) {
    int idx = blockIdx.x * blockDim.x + threadIdx.x;  // over N*32
    if (idx >= N * 32) return;
    int j0 = (idx & 31) * 4;
    float4 h = *(const float4*)&H[(size_t)idx * 4];
    const float* hv = &h.x;
    uint o2[2];
    ushort o[4];
#pragma unroll
    for (int k = 0; k < 4; ++k) {
        float mu  = sums[j0 + k] * invN;
        float var = sums[128 + j0 + k] * invN - mu * mu;
        float v   = (hv[k] - mu) * rsqrtf(var + EPSF);
        o[k] = f2bf(fmaxf(v, 0.f));
    }
    o2[0] = o[0] | ((uint)o[1] << 16);
    o2[1] = o[2] | ((uint)o[3] << 16);
    *(uint2*)&Y[(size_t)idx * 4] = make_uint2(o2[0], o2[1]);
}

// ---------------------------------------------------------------- launch
extern "C" void kernel_launch(void* const* d_in, const int* in_sizes, int n_in,
                              void* d_out, int out_size, void* d_ws, size_t ws_size,
                              hipStream_t stream) {
    const float* x  = (const float*)d_in[0];
    const int*   ei = (const int*)d_in[1];
    const float* ew = (const float*)d_in[2];
    const float* W0 = (const float*)d_in[3];
    const float* W1 = (const float*)d_in[5];
    const float* b1 = (const float*)d_in[6];

    const int N = in_sizes[0] / 128;
    const int E = in_sizes[2];
    const int* row = ei;
    const int* col = ei + E;

    // workspace carve-up (256B aligned)
    uintptr_t base = (uintptr_t)d_ws;
    auto alloc = [&](size_t bytes) {
        uintptr_t p = base;
        base += (bytes + 255) & ~(size_t)255;
        return (void*)p;
    };
    ull*    dc     = (ull*)   alloc((size_t)N * 8);        // packed deg|cnt
    float*  dinv   = (float*) alloc((size_t)N * 4);
    int*    cnt    = (int*)   alloc((size_t)N * 4);
    float*  sums   = (float*) alloc(256 * 4);
    int*    bsums  = (int*)   alloc(1024 * 4);
    int*    rs     = (int*)   alloc((size_t)(N + 1) * 4);
    int*    cursor = (int*)   alloc((size_t)N * 4);
    int2*   sedge  = (int2*)  alloc((size_t)E * 8);        // packed {row, norm}
    ushort* hA     = (ushort*)alloc((size_t)N * 128 * 2);  // bf16 conv sources
    ushort* hB     = (ushort*)alloc((size_t)N * 128 * 2);
    float*  out    = (float*) d_out;
    (void)ws_size; (void)n_in; (void)out_size;

    const float invN = 1.f / (float)N;
    const int nScanBlocks = (N + SCAN_ELEMS - 1) / SCAN_ELEMS;  // 25 for N=100K

    // --- per-call zeroing (harness does not re-poison between replays)
    hipMemsetAsync(dc, 0, (size_t)N * 8, stream);
    hipMemsetAsync(sums, 0, 256 * 4, stream);

    // --- CSR build
    deg_hist_kernel<<<(E + 255) / 256, 256, 0, stream>>>(col, ew, dc, E);
    dc_finalize<<<(N + 255) / 256, 256, 0, stream>>>(dc, dinv, cnt, N);
    scan_phaseA<<<nScanBlocks, 1024, 0, stream>>>(cnt, bsums, N);
    scan_phaseB<<<1, 1024, 0, stream>>>(bsums, nScanBlocks);
    scan_phaseC<<<nScanBlocks, 1024, 0, stream>>>(cnt, bsums, rs, cursor, N, E);
    csr_scatter_kernel<<<(E + 255) / 256, 256, 0, stream>>>(row, col, ew, dinv, cursor,
                                                            sedge, E);

    // --- layer 0: hA(bf16) = x @ W0^T
    gemm128_mfma<false><<<(N + 63) / 64, 256, 0, stream>>>(x, W0, hA, N);

    // --- conv 1: out(f32, d_out scratch) = gather-reduce(hA)
    agg_gather<<<(N + 3) / 4, 256, 0, stream>>>(hA, sedge, rs, nullptr, out, N);

    // --- batchnorm + relu: hB(bf16) = relu(BN(out))   (b0 cancels inside BN)
    bn_stats<<<512, 256, 0, stream>>>(out, sums, N);
    bn_apply<<<(N * 32 + 255) / 256, 256, 0, stream>>>(out, sums, hB, N, invN);

    // --- layer 1: hA(bf16) = hB @ W1^T
    gemm128_mfma<true><<<(N + 63) / 64, 256, 0, stream>>>(hB, W1, hA, N);

    // --- conv 2 (+ b1 folded into accumulator init): out = gather-reduce(hA) + b1
    agg_gather<<<(N + 3) / 4, 256, 0, stream>>>(hA, sedge, rs, b1, out, N);
}

// Round 7
// 342.384 us; speedup vs baseline: 4.9466x; 1.2269x over previous
//
#include <hip/hip_runtime.h>
#include <cstdint>
#include <cstddef>

#define EPSF 1e-5f
#define BKT 256
#define BKT_SHIFT 8
#define SC_E 4096

typedef unsigned long long ull;
typedef __attribute__((ext_vector_type(8))) short bf16x8;
typedef __attribute__((ext_vector_type(4))) float f32x4;

// ================================================================= CSR build
// Bucket = BKT consecutive destination nodes. NB = ceil(N/BKT) (must be <= 512;
// N <= 131072 so row fits in 17 bits, colLow in bits 17..24 of meta).

// --- kernel 1: global per-bucket histogram (LDS-staged)
__global__ __launch_bounds__(512) void bucket_hist(const int* __restrict__ col,
                                                   int* __restrict__ bhist, int E, int NB) {
    __shared__ int lh[512];
    const int t = threadIdx.x;
    lh[t] = 0;
    __syncthreads();
    for (int e = blockIdx.x * 512 + t; e < E; e += gridDim.x * 512)
        atomicAdd(&lh[col[e] >> BKT_SHIFT], 1);
    __syncthreads();
    if (t < NB && lh[t]) atomicAdd(&bhist[t], lh[t]);
}

// --- kernel 2: exclusive scan of bucket counts -> bstart, bcursor; sentinels
__global__ __launch_bounds__(512) void scan_buckets(const int* __restrict__ bhist,
                                                    int* __restrict__ bstart,
                                                    int* __restrict__ bcursor,
                                                    int* __restrict__ rs,
                                                    int NB, int N, int E) {
    __shared__ int part[512];
    const int t = threadIdx.x;
    part[t] = (t < NB) ? bhist[t] : 0;
    __syncthreads();
    for (int off = 1; off < 512; off <<= 1) {
        int v = (t >= off) ? part[t - off] : 0;
        __syncthreads();
        part[t] += v;
        __syncthreads();
    }
    int excl = (t == 0) ? 0 : part[t - 1];
    if (t < NB) { bstart[t] = excl; bcursor[t] = excl; }
    if (t == 0) { bstart[NB] = E; rs[N] = E; }
}

// --- kernel 3: multisplit scatter. Block sorts a 4096-edge chunk by bucket in
// LDS, then writes each bucket's run contiguously (avg ~84B runs -> ~1.5x line
// amplification instead of 8x for naive 8B scattered writes).
__global__ __launch_bounds__(512) void bucket_scatter(const int* __restrict__ row,
                                                      const int* __restrict__ col,
                                                      const float* __restrict__ w,
                                                      int* __restrict__ bcursor,
                                                      int2* __restrict__ brecs,
                                                      int E, int NB) {
    __shared__ int lh[512], lstart[512], lcur[512], gbase[512];
    __shared__ int   sm[SC_E];
    __shared__ float sw[SC_E];
    __shared__ short sb[SC_E];

    const int t = threadIdx.x;
    const int base = blockIdx.x * SC_E;
    const int cnt = min(SC_E, E - base);

    lh[t] = 0;
    __syncthreads();

    int   myb[8], mym[8];
    float myw[8];
#pragma unroll
    for (int k = 0; k < 8; ++k) {
        int i = t + k * 512;  // strided within chunk -> coalesced loads
        if (i < cnt) {
            int e = base + i;
            int r = row[e], c = col[e];
            myb[k] = c >> BKT_SHIFT;
            mym[k] = ((c & (BKT - 1)) << 17) | r;
            myw[k] = w[e];
            atomicAdd(&lh[myb[k]], 1);
        } else myb[k] = -1;
    }
    __syncthreads();

    // exclusive scan of lh -> lstart (Hillis-Steele over 512)
    int v = lh[t];
    lstart[t] = v;
    __syncthreads();
    for (int off = 1; off < 512; off <<= 1) {
        int u = (t >= off) ? lstart[t - off] : 0;
        __syncthreads();
        lstart[t] += u;
        __syncthreads();
    }
    int excl = lstart[t] - v;
    __syncthreads();
    lstart[t] = excl;
    lcur[t]   = excl;
    gbase[t]  = (t < NB) ? atomicAdd(&bcursor[t], v) : 0;
    __syncthreads();

    // place into LDS, sorted by bucket
#pragma unroll
    for (int k = 0; k < 8; ++k) {
        if (myb[k] >= 0) {
            int slot = atomicAdd(&lcur[myb[k]], 1);
            sm[slot] = mym[k];
            sw[slot] = myw[k];
            sb[slot] = (short)myb[k];
        }
    }
    __syncthreads();

    // stream out: consecutive j -> consecutive global pos within each run
    for (int j = t; j < cnt; j += 512) {
        int b = sb[j];
        int pos = gbase[b] + (j - lstart[b]);
        brecs[pos] = make_int2(sm[j], __float_as_int(sw[j]));
    }
}

// --- kernel 4: per-bucket build: per-node counts + weighted degree via LDS
// atomics (no global atomics), local scan -> rs/dinv, node-sorted records.
__global__ __launch_bounds__(256) void bucket_build(const int2* __restrict__ brecs,
                                                    const int* __restrict__ bstart,
                                                    int* __restrict__ rs,
                                                    float* __restrict__ dinv,
                                                    int2* __restrict__ sedge, int N) {
    __shared__ int   lcnt[256], lscan[256], lcur[256];
    __shared__ float ldeg[256];
    const int b = blockIdx.x, t = threadIdx.x;
    const int s = bstart[b], e = bstart[b + 1];
    const int node0 = b << BKT_SHIFT;
    const int nNodes = min(BKT, N - node0);

    lcnt[t] = 0;
    ldeg[t] = 0.f;
    __syncthreads();

    for (int i = s + t; i < e; i += 256) {
        int2 r = brecs[i];
        int cl = r.x >> 17;
        atomicAdd(&lcnt[cl], 1);
        atomicAdd(&ldeg[cl], __int_as_float(r.y));
    }
    __syncthreads();

    int v = lcnt[t];
    lscan[t] = v;
    __syncthreads();
    for (int off = 1; off < 256; off <<= 1) {
        int u = (t >= off) ? lscan[t - off] : 0;
        __syncthreads();
        lscan[t] += u;
        __syncthreads();
    }
    int excl = lscan[t] - v;
    lcur[t] = excl;
    if (t < nNodes) {
        rs[node0 + t] = s + excl;
        float d = ldeg[t];
        dinv[node0 + t] = (d > 0.f) ? rsqrtf(d) : 0.f;
    }
    __syncthreads();

    // node-sorted placement; scattered only within this bucket's ~33KB region
    for (int i = s + t; i < e; i += 256) {
        int2 r = brecs[i];
        int slot = atomicAdd(&lcur[r.x >> 17], 1);
        sedge[s + slot] = r;
    }
}

// --- kernel 5: in-place norm fixup: {meta, w} -> {row, dinv[row]*dinv[c]*w}
__global__ __launch_bounds__(256) void norm_fixup(const int* __restrict__ bstart,
                                                  const float* __restrict__ dinv,
                                                  int2* __restrict__ sedge, int N) {
    __shared__ float ld[256];
    const int b = blockIdx.x, t = threadIdx.x;
    const int node0 = b << BKT_SHIFT;
    const int nNodes = min(BKT, N - node0);
    ld[t] = (t < nNodes) ? dinv[node0 + t] : 0.f;
    const int s = bstart[b], e = bstart[b + 1];
    __syncthreads();
    for (int i = s + t; i < e; i += 256) {
        int2 r = sedge[i];
        int rowi = r.x & 0x1FFFF;
        int cl = r.x >> 17;
        float nrm = dinv[rowi] * ld[cl] * __int_as_float(r.y);
        sedge[i] = make_int2(rowi, __float_as_int(nrm));
    }
}

// ================================================================= GEMM (bf16 MFMA)
__device__ __forceinline__ ushort f2bf(float f) {
    uint b = __float_as_uint(f);
    return (ushort)((b + 0x7FFFu + ((b >> 16) & 1u)) >> 16);  // RNE
}
__device__ __forceinline__ uint4 pack8(const float* f) {
    uint4 o;
    o.x = f2bf(f[0]) | ((uint)f2bf(f[1]) << 16);
    o.y = f2bf(f[2]) | ((uint)f2bf(f[3]) << 16);
    o.z = f2bf(f[4]) | ((uint)f2bf(f[5]) << 16);
    o.w = f2bf(f[6]) | ((uint)f2bf(f[7]) << 16);
    return o;
}

template <bool IN_BF16>
__global__ __launch_bounds__(256) void gemm128_mfma(const void* __restrict__ Xv,
                                                    const float* __restrict__ W,
                                                    ushort* __restrict__ Y, int N) {
    __shared__ __align__(16) ushort Alds[64][128];
    __shared__ __align__(16) ushort Blds[128][128];

    const int t  = threadIdx.x;
    const int n0 = blockIdx.x * 64;

    for (int i = t; i < 128 * 16; i += 256) {
        int j = i >> 4, kc = (i & 15) << 3;
        float f[8];
        *(float4*)&f[0] = *(const float4*)&W[j * 128 + kc];
        *(float4*)&f[4] = *(const float4*)&W[j * 128 + kc + 4];
        *(uint4*)&Blds[j][kc ^ ((j & 7) << 3)] = pack8(f);
    }
    for (int i = t; i < 64 * 16; i += 256) {
        int r = i >> 4, kc = (i & 15) << 3;
        int n = n0 + r;
        uint4 v = make_uint4(0u, 0u, 0u, 0u);
        if (n < N) {
            if constexpr (IN_BF16) {
                v = *(const uint4*)&((const ushort*)Xv)[(size_t)n * 128 + kc];
            } else {
                float f[8];
                *(float4*)&f[0] = *(const float4*)&((const float*)Xv)[(size_t)n * 128 + kc];
                *(float4*)&f[4] = *(const float4*)&((const float*)Xv)[(size_t)n * 128 + kc + 4];
                v = pack8(f);
            }
        }
        *(uint4*)&Alds[r][kc ^ ((r & 7) << 3)] = v;
    }
    __syncthreads();

    const int lane  = t & 63;
    const int wv    = t >> 6;
    const int arow  = wv * 16 + (lane & 15);
    const int klane = (lane >> 4) << 3;
    const int cq    = lane & 15;

    f32x4 acc[8] = {};

    for (int ks = 0; ks < 4; ++ks) {
        const int k0 = ks * 32 + klane;
        bf16x8 a = *(const bf16x8*)&Alds[arow][k0 ^ ((arow & 7) << 3)];
#pragma unroll
        for (int tl = 0; tl < 8; ++tl) {
            int colr = tl * 16 + cq;
            bf16x8 bb = *(const bf16x8*)&Blds[colr][k0 ^ ((colr & 7) << 3)];
            acc[tl] = __builtin_amdgcn_mfma_f32_16x16x32_bf16(a, bb, acc[tl], 0, 0, 0);
        }
    }

    const int r0 = n0 + wv * 16 + ((lane >> 4) << 2);
#pragma unroll
    for (int tl = 0; tl < 8; ++tl) {
#pragma unroll
        for (int reg = 0; reg < 4; ++reg) {
            int rr = r0 + reg;
            if (rr < N) Y[(size_t)rr * 128 + tl * 16 + cq] = f2bf(acc[tl][reg]);
        }
    }
}

// ================================================================= gather conv
__global__ __launch_bounds__(256) void agg_gather(const ushort* __restrict__ Hin,
                                                  const int2* __restrict__ sedge,
                                                  const int* __restrict__ rs,
                                                  const float* __restrict__ bias,
                                                  float* __restrict__ Hout, int N) {
    int c = blockIdx.x * 4 + (threadIdx.x >> 6);
    if (c >= N) return;
    const int lane = threadIdx.x & 63;

    float2 acc;
    if (bias) { acc.x = bias[lane * 2]; acc.y = bias[lane * 2 + 1]; }
    else      { acc.x = 0.f; acc.y = 0.f; }

    int e    = rs[c];
    int eEnd = rs[c + 1];

#define GLOAD(s, nv, vv)                                                       \
    float nv = __int_as_float((s).y);                                         \
    uint  vv = *(const uint*)&Hin[(size_t)(s).x * 128 + lane * 2];

#define GACC(nv, vv)                                                           \
    acc.x = fmaf(nv, __uint_as_float((vv) << 16), acc.x);                      \
    acc.y = fmaf(nv, __uint_as_float((vv) & 0xFFFF0000u), acc.y);

    for (; e + 3 < eEnd; e += 4) {
        int2 s0 = sedge[e], s1 = sedge[e + 1], s2 = sedge[e + 2], s3 = sedge[e + 3];
        GLOAD(s0, n0, v0) GLOAD(s1, n1, v1) GLOAD(s2, n2, v2) GLOAD(s3, n3, v3)
        GACC(n0, v0) GACC(n1, v1) GACC(n2, v2) GACC(n3, v3)
    }
    for (; e < eEnd; ++e) {
        int2 s0 = sedge[e];
        GLOAD(s0, n0, v0)
        GACC(n0, v0)
    }
#undef GLOAD
#undef GACC

    *(float2*)&Hout[(size_t)c * 128 + lane * 2] = acc;
}

// ================================================================= batchnorm
__global__ __launch_bounds__(256) void bn_stats(const float* __restrict__ H,
                                                float* __restrict__ sums, int N) {
    int j = threadIdx.x & 127;
    float s = 0.f, s2 = 0.f;
    for (int n = blockIdx.x * 2 + (threadIdx.x >> 7); n < N; n += gridDim.x * 2) {
        float v = H[(size_t)n * 128 + j];
        s += v; s2 += v * v;
    }
    atomicAdd(&sums[j], s);
    atomicAdd(&sums[128 + j], s2);
}

__global__ __launch_bounds__(256) void bn_apply(const float* __restrict__ H,
                                                const float* __restrict__ sums,
                                                ushort* __restrict__ Y, int N, float invN) {
    int idx = blockIdx.x * blockDim.x + threadIdx.x;  // over N*32
    if (idx >= N * 32) return;
    int j0 = (idx & 31) * 4;
    float4 h = *(const float4*)&H[(size_t)idx * 4];
    const float* hv = &h.x;
    ushort o[4];
#pragma unroll
    for (int k = 0; k < 4; ++k) {
        float mu  = sums[j0 + k] * invN;
        float var = sums[128 + j0 + k] * invN - mu * mu;
        float v   = (hv[k] - mu) * rsqrtf(var + EPSF);
        o[k] = f2bf(fmaxf(v, 0.f));
    }
    *(uint2*)&Y[(size_t)idx * 4] =
        make_uint2(o[0] | ((uint)o[1] << 16), o[2] | ((uint)o[3] << 16));
}

// ================================================================= launch
extern "C" void kernel_launch(void* const* d_in, const int* in_sizes, int n_in,
                              void* d_out, int out_size, void* d_ws, size_t ws_size,
                              hipStream_t stream) {
    const float* x  = (const float*)d_in[0];
    const int*   ei = (const int*)d_in[1];
    const float* ew = (const float*)d_in[2];
    const float* W0 = (const float*)d_in[3];
    const float* W1 = (const float*)d_in[5];
    const float* b1 = (const float*)d_in[6];

    const int N = in_sizes[0] / 128;
    const int E = in_sizes[2];
    const int* row = ei;
    const int* col = ei + E;
    const int NB = (N + BKT - 1) >> BKT_SHIFT;  // 391 for N=100K (<=512 required)

    // workspace carve-up (256B aligned)
    uintptr_t base = (uintptr_t)d_ws;
    auto alloc = [&](size_t bytes) {
        uintptr_t p = base;
        base += (bytes + 255) & ~(size_t)255;
        return (void*)p;
    };
    float*  dinv   = (float*) alloc((size_t)N * 4);
    float*  sums   = (float*) alloc(256 * 4);
    int*    bhist  = (int*)   alloc((size_t)(NB + 1) * 4);
    int*    bstart = (int*)   alloc((size_t)(NB + 1) * 4);
    int*    bcursor= (int*)   alloc((size_t)NB * 4);
    int*    rs     = (int*)   alloc((size_t)(N + 1) * 4);
    int2*   sedge  = (int2*)  alloc((size_t)E * 8);        // final {row, norm}
    ushort* hA     = (ushort*)alloc((size_t)N * 128 * 2);  // bf16 conv sources
    ushort* hB     = (ushort*)alloc((size_t)N * 128 * 2);
    // brecs (bucket-partitioned temp records) aliases hB: hB is first written
    // by bn_apply, long after the CSR build has consumed brecs.
    int2*   brecs  = (int2*)hB;
    float*  out    = (float*) d_out;
    (void)ws_size; (void)n_in; (void)out_size;

    const float invN = 1.f / (float)N;

    // --- per-call zeroing (harness does not re-poison between replays)
    hipMemsetAsync(bhist, 0, (size_t)(NB + 1) * 4, stream);
    hipMemsetAsync(sums, 0, 256 * 4, stream);

    // --- CSR build: bucket hist -> scan -> multisplit scatter -> per-bucket
    //     build (counts+deg via LDS atomics) -> norm fixup
    bucket_hist<<<1024, 512, 0, stream>>>(col, bhist, E, NB);
    scan_buckets<<<1, 512, 0, stream>>>(bhist, bstart, bcursor, rs, NB, N, E);
    bucket_scatter<<<(E + SC_E - 1) / SC_E, 512, 0, stream>>>(row, col, ew, bcursor,
                                                              brecs, E, NB);
    bucket_build<<<NB, 256, 0, stream>>>(brecs, bstart, rs, dinv, sedge, N);
    norm_fixup<<<NB, 256, 0, stream>>>(bstart, dinv, sedge, N);

    // --- layer 0: hA(bf16) = x @ W0^T
    gemm128_mfma<false><<<(N + 63) / 64, 256, 0, stream>>>(x, W0, hA, N);

    // --- conv 1: out(f32, d_out scratch) = gather-reduce(hA)
    agg_gather<<<(N + 3) / 4, 256, 0, stream>>>(hA, sedge, rs, nullptr, out, N);

    // --- batchnorm + relu: hB(bf16) = relu(BN(out))   (b0 cancels inside BN)
    bn_stats<<<512, 256, 0, stream>>>(out, sums, N);
    bn_apply<<<(N * 32 + 255) / 256, 256, 0, stream>>>(out, sums, hB, N, invN);

    // --- layer 1: hA(bf16) = hB @ W1^T
    gemm128_mfma<true><<<(N + 63) / 64, 256, 0, stream>>>(hB, W1, hA, N);

    // --- conv 2 (+ b1 folded into accumulator init)
    agg_gather<<<(N + 3) / 4, 256, 0, stream>>>(hA, sedge, rs, b1, out, N);
}

// Round 8
// 305.625 us; speedup vs baseline: 5.5416x; 1.1203x over previous
//
#include <hip/hip_runtime.h>
#include <cstdint>
#include <cstddef>

#define EPSF 1e-5f
#define BKT 256
#define BKT_SHIFT 8
#define SC_E 4096

typedef unsigned long long ull;
typedef __attribute__((ext_vector_type(8))) short bf16x8;
typedef __attribute__((ext_vector_type(4))) float f32x4;

// ================================================================= CSR build
// Bucket = BKT consecutive destination nodes. NB = ceil(N/BKT) <= 512.
// meta = (colLow << 17) | row  (N <= 131072).

__global__ __launch_bounds__(512) void bucket_hist(const int* __restrict__ col,
                                                   int* __restrict__ bhist, int E, int NB) {
    __shared__ int lh[512];
    const int t = threadIdx.x;
    lh[t] = 0;
    __syncthreads();
    for (int e = blockIdx.x * 512 + t; e < E; e += gridDim.x * 512)
        atomicAdd(&lh[col[e] >> BKT_SHIFT], 1);
    __syncthreads();
    if (t < NB && lh[t]) atomicAdd(&bhist[t], lh[t]);
}

__global__ __launch_bounds__(512) void scan_buckets(const int* __restrict__ bhist,
                                                    int* __restrict__ bstart,
                                                    int* __restrict__ bcursor,
                                                    int* __restrict__ rs,
                                                    int NB, int N, int E) {
    __shared__ int part[512];
    const int t = threadIdx.x;
    part[t] = (t < NB) ? bhist[t] : 0;
    __syncthreads();
    for (int off = 1; off < 512; off <<= 1) {
        int v = (t >= off) ? part[t - off] : 0;
        __syncthreads();
        part[t] += v;
        __syncthreads();
    }
    int excl = (t == 0) ? 0 : part[t - 1];
    if (t < NB) { bstart[t] = excl; bcursor[t] = excl; }
    if (t == 0) { bstart[NB] = E; rs[N] = E; }
}

// multisplit scatter: LDS-sort a 4096-edge chunk by bucket, write runs contiguously
__global__ __launch_bounds__(512) void bucket_scatter(const int* __restrict__ row,
                                                      const int* __restrict__ col,
                                                      const float* __restrict__ w,
                                                      int* __restrict__ bcursor,
                                                      int2* __restrict__ brecs,
                                                      int E, int NB) {
    __shared__ int lh[512], lstart[512], lcur[512], gbase[512];
    __shared__ int   sm[SC_E];
    __shared__ float sw[SC_E];
    __shared__ short sb[SC_E];

    const int t = threadIdx.x;
    const int base = blockIdx.x * SC_E;
    const int cnt = min(SC_E, E - base);

    lh[t] = 0;
    __syncthreads();

    int   myb[8], mym[8];
    float myw[8];
#pragma unroll
    for (int k = 0; k < 8; ++k) {
        int i = t + k * 512;
        if (i < cnt) {
            int e = base + i;
            int r = row[e], c = col[e];
            myb[k] = c >> BKT_SHIFT;
            mym[k] = ((c & (BKT - 1)) << 17) | r;
            myw[k] = w[e];
            atomicAdd(&lh[myb[k]], 1);
        } else myb[k] = -1;
    }
    __syncthreads();

    int v = lh[t];
    lstart[t] = v;
    __syncthreads();
    for (int off = 1; off < 512; off <<= 1) {
        int u = (t >= off) ? lstart[t - off] : 0;
        __syncthreads();
        lstart[t] += u;
        __syncthreads();
    }
    int excl = lstart[t] - v;
    __syncthreads();
    lstart[t] = excl;
    lcur[t]   = excl;
    gbase[t]  = (t < NB) ? atomicAdd(&bcursor[t], v) : 0;
    __syncthreads();

#pragma unroll
    for (int k = 0; k < 8; ++k) {
        if (myb[k] >= 0) {
            int slot = atomicAdd(&lcur[myb[k]], 1);
            sm[slot] = mym[k];
            sw[slot] = myw[k];
            sb[slot] = (short)myb[k];
        }
    }
    __syncthreads();

    for (int j = t; j < cnt; j += 512) {
        int b = sb[j];
        int pos = gbase[b] + (j - lstart[b]);
        brecs[pos] = make_int2(sm[j], __float_as_int(sw[j]));
    }
}

// per-bucket: node counts + weighted degree via LDS atomics, local scan -> rs/dinv
__global__ __launch_bounds__(256) void bucket_build(const int2* __restrict__ brecs,
                                                    const int* __restrict__ bstart,
                                                    int* __restrict__ rs,
                                                    float* __restrict__ dinv,
                                                    int2* __restrict__ sedge, int N) {
    __shared__ int   lcnt[256], lscan[256], lcur[256];
    __shared__ float ldeg[256];
    const int b = blockIdx.x, t = threadIdx.x;
    const int s = bstart[b], e = bstart[b + 1];
    const int node0 = b << BKT_SHIFT;
    const int nNodes = min(BKT, N - node0);

    lcnt[t] = 0;
    ldeg[t] = 0.f;
    __syncthreads();

    for (int i = s + t; i < e; i += 256) {
        int2 r = brecs[i];
        int cl = r.x >> 17;
        atomicAdd(&lcnt[cl], 1);
        atomicAdd(&ldeg[cl], __int_as_float(r.y));
    }
    __syncthreads();

    int v = lcnt[t];
    lscan[t] = v;
    __syncthreads();
    for (int off = 1; off < 256; off <<= 1) {
        int u = (t >= off) ? lscan[t - off] : 0;
        __syncthreads();
        lscan[t] += u;
        __syncthreads();
    }
    int excl = lscan[t] - v;
    lcur[t] = excl;
    if (t < nNodes) {
        rs[node0 + t] = s + excl;
        float d = ldeg[t];
        dinv[node0 + t] = (d > 0.f) ? rsqrtf(d) : 0.f;
    }
    __syncthreads();

    for (int i = s + t; i < e; i += 256) {
        int2 r = brecs[i];
        int slot = atomicAdd(&lcur[r.x >> 17], 1);
        sedge[s + slot] = r;
    }
}

// in-place norm fixup: {meta, w} -> {row, dinv[row]*dinv[c]*w}
__global__ __launch_bounds__(256) void norm_fixup(const int* __restrict__ bstart,
                                                  const float* __restrict__ dinv,
                                                  int2* __restrict__ sedge, int N) {
    __shared__ float ld[256];
    const int b = blockIdx.x, t = threadIdx.x;
    const int node0 = b << BKT_SHIFT;
    const int nNodes = min(BKT, N - node0);
    ld[t] = (t < nNodes) ? dinv[node0 + t] : 0.f;
    const int s = bstart[b], e = bstart[b + 1];
    __syncthreads();
    for (int i = s + t; i < e; i += 256) {
        int2 r = sedge[i];
        int rowi = r.x & 0x1FFFF;
        int cl = r.x >> 17;
        float nrm = dinv[rowi] * ld[cl] * __int_as_float(r.y);
        sedge[i] = make_int2(rowi, __float_as_int(nrm));
    }
}

// ================================================================= GEMM (bf16 MFMA)
__device__ __forceinline__ ushort f2bf(float f) {
    uint b = __float_as_uint(f);
    return (ushort)((b + 0x7FFFu + ((b >> 16) & 1u)) >> 16);  // RNE
}
__device__ __forceinline__ float bf2f(ushort u) {
    return __uint_as_float((uint)u << 16);
}
__device__ __forceinline__ uint4 pack8(const float* f) {
    uint4 o;
    o.x = f2bf(f[0]) | ((uint)f2bf(f[1]) << 16);
    o.y = f2bf(f[2]) | ((uint)f2bf(f[3]) << 16);
    o.z = f2bf(f[4]) | ((uint)f2bf(f[5]) << 16);
    o.w = f2bf(f[6]) | ((uint)f2bf(f[7]) << 16);
    return o;
}

// MODE 0: X = f32, plain. MODE 2: X = bf16, apply BN(sums,invN)+ReLU during staging.
template <int MODE>
__global__ __launch_bounds__(256) void gemm128_mfma(const void* __restrict__ Xv,
                                                    const float* __restrict__ W,
                                                    ushort* __restrict__ Y, int N,
                                                    const float* __restrict__ sums,
                                                    float invN) {
    __shared__ __align__(16) ushort Alds[64][128];
    __shared__ __align__(16) ushort Blds[128][128];
    __shared__ float bnmu[128], bnrs[128];

    const int t  = threadIdx.x;
    const int n0 = blockIdx.x * 64;

    if constexpr (MODE == 2) {
        if (t < 128) {
            float mu  = sums[t] * invN;
            float var = sums[128 + t] * invN - mu * mu;
            bnmu[t] = mu;
            bnrs[t] = rsqrtf(var + EPSF);
        }
        __syncthreads();
    }

    for (int i = t; i < 128 * 16; i += 256) {
        int j = i >> 4, kc = (i & 15) << 3;
        float f[8];
        *(float4*)&f[0] = *(const float4*)&W[j * 128 + kc];
        *(float4*)&f[4] = *(const float4*)&W[j * 128 + kc + 4];
        *(uint4*)&Blds[j][kc ^ ((j & 7) << 3)] = pack8(f);
    }
    for (int i = t; i < 64 * 16; i += 256) {
        int r = i >> 4, kc = (i & 15) << 3;
        int n = n0 + r;
        uint4 v = make_uint4(0u, 0u, 0u, 0u);
        if (n < N) {
            if constexpr (MODE == 0) {
                float f[8];
                *(float4*)&f[0] = *(const float4*)&((const float*)Xv)[(size_t)n * 128 + kc];
                *(float4*)&f[4] = *(const float4*)&((const float*)Xv)[(size_t)n * 128 + kc + 4];
                v = pack8(f);
            } else {
                uint4 raw = *(const uint4*)&((const ushort*)Xv)[(size_t)n * 128 + kc];
                const uint* rw = &raw.x;
                float f[8];
#pragma unroll
                for (int k = 0; k < 4; ++k) {
                    float lo = __uint_as_float(rw[k] << 16);
                    float hi = __uint_as_float(rw[k] & 0xFFFF0000u);
                    f[2 * k]     = fmaxf((lo - bnmu[kc + 2 * k])     * bnrs[kc + 2 * k],     0.f);
                    f[2 * k + 1] = fmaxf((hi - bnmu[kc + 2 * k + 1]) * bnrs[kc + 2 * k + 1], 0.f);
                }
                v = pack8(f);
            }
        }
        *(uint4*)&Alds[r][kc ^ ((r & 7) << 3)] = v;
    }
    __syncthreads();

    const int lane  = t & 63;
    const int wv    = t >> 6;
    const int arow  = wv * 16 + (lane & 15);
    const int klane = (lane >> 4) << 3;
    const int cq    = lane & 15;

    f32x4 acc[8] = {};

    for (int ks = 0; ks < 4; ++ks) {
        const int k0 = ks * 32 + klane;
        bf16x8 a = *(const bf16x8*)&Alds[arow][k0 ^ ((arow & 7) << 3)];
#pragma unroll
        for (int tl = 0; tl < 8; ++tl) {
            int colr = tl * 16 + cq;
            bf16x8 bb = *(const bf16x8*)&Blds[colr][k0 ^ ((colr & 7) << 3)];
            acc[tl] = __builtin_amdgcn_mfma_f32_16x16x32_bf16(a, bb, acc[tl], 0, 0, 0);
        }
    }

    const int r0 = n0 + wv * 16 + ((lane >> 4) << 2);
#pragma unroll
    for (int tl = 0; tl < 8; ++tl) {
#pragma unroll
        for (int reg = 0; reg < 4; ++reg) {
            int rr = r0 + reg;
            if (rr < N) Y[(size_t)rr * 128 + tl * 16 + cq] = f2bf(acc[tl][reg]);
        }
    }
}

// ================================================================= gather conv
// one wave per dest node; lane L owns features [2L,2L+1]. Lane L also holds edge
// record e0+L -> ONE coalesced 512B sedge read covers deg<=64; __shfl broadcasts.
__device__ __forceinline__ float bflo(uint v) { return __uint_as_float(v << 16); }
__device__ __forceinline__ float bfhi(uint v) { return __uint_as_float(v & 0xFFFF0000u); }

template <bool OUT_BF16>
__global__ __launch_bounds__(256) void agg_gather(const ushort* __restrict__ Hin,
                                                  const int2* __restrict__ sedge,
                                                  const int* __restrict__ rs,
                                                  const float* __restrict__ bias,
                                                  void* __restrict__ Hout, int N, int E) {
    int c = blockIdx.x * 4 + (threadIdx.x >> 6);
    if (c >= N) return;
    const int lane = threadIdx.x & 63;

    float2 acc;
    if (bias) { acc.x = bias[lane * 2]; acc.y = bias[lane * 2 + 1]; }
    else      { acc.x = 0.f; acc.y = 0.f; }

    const int e0 = rs[c];
    const int deg = rs[c + 1] - e0;

    for (int base = 0; base < deg; base += 64) {
        int m = min(64, deg - base);
        int idx = e0 + base + lane;
        int2 rec = sedge[idx < E ? idx : E - 1];

        int j = 0;
        for (; j + 3 < m; j += 4) {
            int   r0 = __shfl(rec.x, j),     r1 = __shfl(rec.x, j + 1);
            int   r2 = __shfl(rec.x, j + 2), r3 = __shfl(rec.x, j + 3);
            float w0 = __int_as_float(__shfl(rec.y, j));
            float w1 = __int_as_float(__shfl(rec.y, j + 1));
            float w2 = __int_as_float(__shfl(rec.y, j + 2));
            float w3 = __int_as_float(__shfl(rec.y, j + 3));
            uint v0 = *(const uint*)&Hin[(size_t)r0 * 128 + lane * 2];
            uint v1 = *(const uint*)&Hin[(size_t)r1 * 128 + lane * 2];
            uint v2 = *(const uint*)&Hin[(size_t)r2 * 128 + lane * 2];
            uint v3 = *(const uint*)&Hin[(size_t)r3 * 128 + lane * 2];
            acc.x = fmaf(w0, bflo(v0), acc.x); acc.y = fmaf(w0, bfhi(v0), acc.y);
            acc.x = fmaf(w1, bflo(v1), acc.x); acc.y = fmaf(w1, bfhi(v1), acc.y);
            acc.x = fmaf(w2, bflo(v2), acc.x); acc.y = fmaf(w2, bfhi(v2), acc.y);
            acc.x = fmaf(w3, bflo(v3), acc.x); acc.y = fmaf(w3, bfhi(v3), acc.y);
        }
        for (; j < m; ++j) {
            int   r0 = __shfl(rec.x, j);
            float w0 = __int_as_float(__shfl(rec.y, j));
            uint v0 = *(const uint*)&Hin[(size_t)r0 * 128 + lane * 2];
            acc.x = fmaf(w0, bflo(v0), acc.x); acc.y = fmaf(w0, bfhi(v0), acc.y);
        }
    }

    if constexpr (OUT_BF16) {
        ((uint*)Hout)[(size_t)c * 64 + lane] = f2bf(acc.x) | ((uint)f2bf(acc.y) << 16);
    } else {
        *(float2*)&((float*)Hout)[(size_t)c * 128 + lane * 2] = acc;
    }
}

// ================================================================= batchnorm stats (bf16 in)
__global__ __launch_bounds__(256) void bn_stats(const ushort* __restrict__ H,
                                                float* __restrict__ sums, int N) {
    int j = threadIdx.x & 127;
    float s = 0.f, s2 = 0.f;
    for (int n = blockIdx.x * 2 + (threadIdx.x >> 7); n < N; n += gridDim.x * 2) {
        float v = bf2f(H[(size_t)n * 128 + j]);
        s += v; s2 += v * v;
    }
    atomicAdd(&sums[j], s);
    atomicAdd(&sums[128 + j], s2);
}

// ================================================================= launch
extern "C" void kernel_launch(void* const* d_in, const int* in_sizes, int n_in,
                              void* d_out, int out_size, void* d_ws, size_t ws_size,
                              hipStream_t stream) {
    const float* x  = (const float*)d_in[0];
    const int*   ei = (const int*)d_in[1];
    const float* ew = (const float*)d_in[2];
    const float* W0 = (const float*)d_in[3];
    const float* W1 = (const float*)d_in[5];
    const float* b1 = (const float*)d_in[6];

    const int N = in_sizes[0] / 128;
    const int E = in_sizes[2];
    const int* row = ei;
    const int* col = ei + E;
    const int NB = (N + BKT - 1) >> BKT_SHIFT;  // 391 for N=100K (<=512 required)

    uintptr_t base = (uintptr_t)d_ws;
    auto alloc = [&](size_t bytes) {
        uintptr_t p = base;
        base += (bytes + 255) & ~(size_t)255;
        return (void*)p;
    };
    float*  dinv   = (float*) alloc((size_t)N * 4);
    float*  sums   = (float*) alloc(256 * 4);
    int*    bhist  = (int*)   alloc((size_t)(NB + 1) * 4);
    int*    bstart = (int*)   alloc((size_t)(NB + 1) * 4);
    int*    bcursor= (int*)   alloc((size_t)NB * 4);
    int*    rs     = (int*)   alloc((size_t)(N + 1) * 4);
    int2*   sedge  = (int2*)  alloc((size_t)E * 8);        // final {row, norm}
    ushort* hA     = (ushort*)alloc((size_t)N * 128 * 2);  // bf16 feature buffers
    ushort* hB     = (ushort*)alloc((size_t)N * 128 * 2);
    // brecs (bucket-partitioned temps) aliases hB: hB first written by conv1,
    // long after bucket_build consumed brecs.
    int2*   brecs  = (int2*)hB;
    float*  out    = (float*) d_out;
    (void)ws_size; (void)n_in; (void)out_size;

    const float invN = 1.f / (float)N;

    // per-call zeroing (harness does not re-poison between replays)
    hipMemsetAsync(bhist, 0, (size_t)(NB + 1) * 4, stream);
    hipMemsetAsync(sums, 0, 256 * 4, stream);

    // --- CSR build
    bucket_hist<<<1024, 512, 0, stream>>>(col, bhist, E, NB);
    scan_buckets<<<1, 512, 0, stream>>>(bhist, bstart, bcursor, rs, NB, N, E);
    bucket_scatter<<<(E + SC_E - 1) / SC_E, 512, 0, stream>>>(row, col, ew, bcursor,
                                                              brecs, E, NB);
    bucket_build<<<NB, 256, 0, stream>>>(brecs, bstart, rs, dinv, sedge, N);
    norm_fixup<<<NB, 256, 0, stream>>>(bstart, dinv, sedge, N);

    // --- layer 0: hA(bf16) = x @ W0^T
    gemm128_mfma<0><<<(N + 63) / 64, 256, 0, stream>>>(x, W0, hA, N, nullptr, 0.f);

    // --- conv 1: hB(bf16) = gather-reduce(hA)
    agg_gather<true><<<(N + 3) / 4, 256, 0, stream>>>(hA, sedge, rs, nullptr, hB, N, E);

    // --- BN stats on bf16 conv output (b0 cancels inside BN)
    bn_stats<<<512, 256, 0, stream>>>(hB, sums, N);

    // --- layer 1 (BN+ReLU fused into A-staging): hA(bf16) = relu(BN(hB)) @ W1^T
    gemm128_mfma<2><<<(N + 63) / 64, 256, 0, stream>>>(hB, W1, hA, N, sums, invN);

    // --- conv 2 (+ b1): out(f32) = gather-reduce(hA) + b1
    agg_gather<false><<<(N + 3) / 4, 256, 0, stream>>>(hA, sedge, rs, b1, out, N, E);
}

// Round 10
// 293.577 us; speedup vs baseline: 5.7690x; 1.0410x over previous
//
#include <hip/hip_runtime.h>
#include <cstdint>
#include <cstddef>

#define EPSF 1e-5f
#define BKT 256
#define BKT_SHIFT 8
#define SC_E 4096

typedef unsigned long long ull;
typedef __attribute__((ext_vector_type(8))) short bf16x8;
typedef __attribute__((ext_vector_type(4))) float f32x4;

// ================================================================= CSR build
// Bucket = BKT consecutive destination nodes. NB = ceil(N/BKT) <= 512.
// meta = (colLow << 17) | row  (N <= 131072).

__global__ __launch_bounds__(512) void bucket_hist(const int* __restrict__ col,
                                                   int* __restrict__ bhist, int E, int NB) {
    __shared__ int lh[512];
    const int t = threadIdx.x;
    lh[t] = 0;
    __syncthreads();
    for (int e = blockIdx.x * 512 + t; e < E; e += gridDim.x * 512)
        atomicAdd(&lh[col[e] >> BKT_SHIFT], 1);
    __syncthreads();
    if (t < NB && lh[t]) atomicAdd(&bhist[t], lh[t]);
}

__global__ __launch_bounds__(512) void scan_buckets(const int* __restrict__ bhist,
                                                    int* __restrict__ bstart,
                                                    int* __restrict__ bcursor,
                                                    int* __restrict__ rs,
                                                    int NB, int N, int E) {
    __shared__ int part[512];
    const int t = threadIdx.x;
    part[t] = (t < NB) ? bhist[t] : 0;
    __syncthreads();
    for (int off = 1; off < 512; off <<= 1) {
        int v = (t >= off) ? part[t - off] : 0;
        __syncthreads();
        part[t] += v;
        __syncthreads();
    }
    int excl = (t == 0) ? 0 : part[t - 1];
    if (t < NB) { bstart[t] = excl; bcursor[t] = excl; }
    if (t == 0) { bstart[NB] = E; rs[N] = E; }
}

// multisplit scatter: LDS-sort a 4096-edge chunk by bucket, write runs contiguously
__global__ __launch_bounds__(512) void bucket_scatter(const int* __restrict__ row,
                                                      const int* __restrict__ col,
                                                      const float* __restrict__ w,
                                                      int* __restrict__ bcursor,
                                                      int2* __restrict__ brecs,
                                                      int E, int NB) {
    __shared__ int lh[512], lstart[512], lcur[512], gbase[512];
    __shared__ int   sm[SC_E];
    __shared__ float sw[SC_E];
    __shared__ short sb[SC_E];

    const int t = threadIdx.x;
    const int base = blockIdx.x * SC_E;
    const int cnt = min(SC_E, E - base);

    lh[t] = 0;
    __syncthreads();

    int   myb[8], mym[8];
    float myw[8];
#pragma unroll
    for (int k = 0; k < 8; ++k) {
        int i = t + k * 512;
        if (i < cnt) {
            int e = base + i;
            int r = row[e], c = col[e];
            myb[k] = c >> BKT_SHIFT;
            mym[k] = ((c & (BKT - 1)) << 17) | r;
            myw[k] = w[e];
            atomicAdd(&lh[myb[k]], 1);
        } else myb[k] = -1;
    }
    __syncthreads();

    int v = lh[t];
    lstart[t] = v;
    __syncthreads();
    for (int off = 1; off < 512; off <<= 1) {
        int u = (t >= off) ? lstart[t - off] : 0;
        __syncthreads();
        lstart[t] += u;
        __syncthreads();
    }
    int excl = lstart[t] - v;
    __syncthreads();
    lstart[t] = excl;
    lcur[t]   = excl;
    gbase[t]  = (t < NB) ? atomicAdd(&bcursor[t], v) : 0;
    __syncthreads();

#pragma unroll
    for (int k = 0; k < 8; ++k) {
        if (myb[k] >= 0) {
            int slot = atomicAdd(&lcur[myb[k]], 1);
            sm[slot] = mym[k];
            sw[slot] = myw[k];
            sb[slot] = (short)myb[k];
        }
    }
    __syncthreads();

    for (int j = t; j < cnt; j += 512) {
        int b = sb[j];
        int pos = gbase[b] + (j - lstart[b]);
        brecs[pos] = make_int2(sm[j], __float_as_int(sw[j]));
    }
}

// pass 1: per-node counts + weighted degree via LDS atomics -> rs, dinv
__global__ __launch_bounds__(256) void bucket_build_p1(const int2* __restrict__ brecs,
                                                       const int* __restrict__ bstart,
                                                       int* __restrict__ rs,
                                                       float* __restrict__ dinv, int N) {
    __shared__ int   lcnt[256], lscan[256];
    __shared__ float ldeg[256];
    const int b = blockIdx.x, t = threadIdx.x;
    const int s = bstart[b], e = bstart[b + 1];
    const int node0 = b << BKT_SHIFT;
    const int nNodes = min(BKT, N - node0);

    lcnt[t] = 0;
    ldeg[t] = 0.f;
    __syncthreads();

    for (int i = s + t; i < e; i += 256) {
        int2 r = brecs[i];
        int cl = r.x >> 17;
        atomicAdd(&lcnt[cl], 1);
        atomicAdd(&ldeg[cl], __int_as_float(r.y));
    }
    __syncthreads();

    int v = lcnt[t];
    lscan[t] = v;
    __syncthreads();
    for (int off = 1; off < 256; off <<= 1) {
        int u = (t >= off) ? lscan[t - off] : 0;
        __syncthreads();
        lscan[t] += u;
        __syncthreads();
    }
    if (t < nNodes) {
        rs[node0 + t] = s + (lscan[t] - v);
        float d = ldeg[t];
        dinv[node0 + t] = (d > 0.f) ? rsqrtf(d) : 0.f;
    }
}

// pass 2: node-sorted placement WITH norm computed in the same pass
__global__ __launch_bounds__(256) void bucket_place(const int2* __restrict__ brecs,
                                                    const int* __restrict__ bstart,
                                                    const int* __restrict__ rs,
                                                    const float* __restrict__ dinv,
                                                    int2* __restrict__ sedge, int N) {
    __shared__ int   lcur[256];
    __shared__ float ld[256];
    const int b = blockIdx.x, t = threadIdx.x;
    const int s = bstart[b], e = bstart[b + 1];
    const int node0 = b << BKT_SHIFT;
    const int nNodes = min(BKT, N - node0);

    lcur[t] = (t < nNodes) ? rs[node0 + t] : 0;
    ld[t]   = (t < nNodes) ? dinv[node0 + t] : 0.f;
    __syncthreads();

    for (int i = s + t; i < e; i += 256) {
        int2 r = brecs[i];
        int cl   = r.x >> 17;
        int rowi = r.x & 0x1FFFF;
        float nrm = dinv[rowi] * ld[cl] * __int_as_float(r.y);
        int slot = atomicAdd(&lcur[cl], 1);
        sedge[slot] = make_int2(rowi, __float_as_int(nrm));
    }
}

// ================================================================= GEMM (bf16 MFMA)
__device__ __forceinline__ ushort f2bf(float f) {
    uint b = __float_as_uint(f);
    return (ushort)((b + 0x7FFFu + ((b >> 16) & 1u)) >> 16);  // RNE
}
__device__ __forceinline__ float bf2f(ushort u) {
    return __uint_as_float((uint)u << 16);
}
__device__ __forceinline__ uint4 pack8(const float* f) {
    uint4 o;
    o.x = f2bf(f[0]) | ((uint)f2bf(f[1]) << 16);
    o.y = f2bf(f[2]) | ((uint)f2bf(f[3]) << 16);
    o.z = f2bf(f[4]) | ((uint)f2bf(f[5]) << 16);
    o.w = f2bf(f[6]) | ((uint)f2bf(f[7]) << 16);
    return o;
}

// Persistent-W: W (and BN prologue for MODE 2) staged ONCE per block; block then
// loops over row-tiles with stride gridDim.x.
template <int MODE>
__global__ __launch_bounds__(256) void gemm128_mfma(const void* __restrict__ Xv,
                                                    const float* __restrict__ W,
                                                    ushort* __restrict__ Y, int N,
                                                    const float* __restrict__ sums,
                                                    float invN) {
    __shared__ __align__(16) ushort Alds[64][128];
    __shared__ __align__(16) ushort Blds[128][128];
    __shared__ float bnmu[128], bnrs[128];

    const int t = threadIdx.x;

    if constexpr (MODE == 2) {
        if (t < 128) {
            float mu  = sums[t] * invN;
            float var = sums[128 + t] * invN - mu * mu;
            bnmu[t] = mu;
            bnrs[t] = rsqrtf(var + EPSF);
        }
    }

    for (int i = t; i < 128 * 16; i += 256) {
        int j = i >> 4, kc = (i & 15) << 3;
        float f[8];
        *(float4*)&f[0] = *(const float4*)&W[j * 128 + kc];
        *(float4*)&f[4] = *(const float4*)&W[j * 128 + kc + 4];
        *(uint4*)&Blds[j][kc ^ ((j & 7) << 3)] = pack8(f);
    }

    const int lane  = t & 63;
    const int wv    = t >> 6;
    const int arow  = wv * 16 + (lane & 15);
    const int klane = (lane >> 4) << 3;
    const int cq    = lane & 15;
    const int nTiles = (N + 63) >> 6;

    for (int tile = blockIdx.x; tile < nTiles; tile += gridDim.x) {
        const int n0 = tile * 64;
        __syncthreads();  // W/bnmu visible (1st iter); prior MFMA reads done (later)

        for (int i = t; i < 64 * 16; i += 256) {
            int r = i >> 4, kc = (i & 15) << 3;
            int n = n0 + r;
            uint4 v = make_uint4(0u, 0u, 0u, 0u);
            if (n < N) {
                if constexpr (MODE == 0) {
                    float f[8];
                    *(float4*)&f[0] = *(const float4*)&((const float*)Xv)[(size_t)n * 128 + kc];
                    *(float4*)&f[4] = *(const float4*)&((const float*)Xv)[(size_t)n * 128 + kc + 4];
                    v = pack8(f);
                } else {
                    uint4 raw = *(const uint4*)&((const ushort*)Xv)[(size_t)n * 128 + kc];
                    const uint* rw = &raw.x;
                    float f[8];
#pragma unroll
                    for (int k = 0; k < 4; ++k) {
                        float lo = __uint_as_float(rw[k] << 16);
                        float hi = __uint_as_float(rw[k] & 0xFFFF0000u);
                        f[2 * k]     = fmaxf((lo - bnmu[kc + 2 * k])     * bnrs[kc + 2 * k],     0.f);
                        f[2 * k + 1] = fmaxf((hi - bnmu[kc + 2 * k + 1]) * bnrs[kc + 2 * k + 1], 0.f);
                    }
                    v = pack8(f);
                }
            }
            *(uint4*)&Alds[r][kc ^ ((r & 7) << 3)] = v;
        }
        __syncthreads();

        f32x4 acc[8] = {};
        for (int ks = 0; ks < 4; ++ks) {
            const int k0 = ks * 32 + klane;
            bf16x8 a = *(const bf16x8*)&Alds[arow][k0 ^ ((arow & 7) << 3)];
#pragma unroll
            for (int tl = 0; tl < 8; ++tl) {
                int colr = tl * 16 + cq;
                bf16x8 bb = *(const bf16x8*)&Blds[colr][k0 ^ ((colr & 7) << 3)];
                acc[tl] = __builtin_amdgcn_mfma_f32_16x16x32_bf16(a, bb, acc[tl], 0, 0, 0);
            }
        }

        const int r0 = n0 + wv * 16 + ((lane >> 4) << 2);
#pragma unroll
        for (int tl = 0; tl < 8; ++tl) {
#pragma unroll
            for (int reg = 0; reg < 4; ++reg) {
                int rr = r0 + reg;
                if (rr < N) Y[(size_t)rr * 128 + tl * 16 + cq] = f2bf(acc[tl][reg]);
            }
        }
    }
}

// ================================================================= gather conv
// one wave per dest node. Half-wave pairing: lane (h, lq) loads uint2 =
// features [4lq..4lq+3] of edge (j+h) -> one vmem op moves 2 full 256B rows.
// ALL __shfl ops are unconditional with in-range sources (<m), so every source
// lane is exec-active (round-9 bug: shfl under divergence read an inactive
// lane -> undefined weight for odd-tail degrees >= 33).
__device__ __forceinline__ float bflo(uint v) { return __uint_as_float(v << 16); }
__device__ __forceinline__ float bfhi(uint v) { return __uint_as_float(v & 0xFFFF0000u); }

template <bool OUT_BF16>
__global__ __launch_bounds__(256) void agg_gather(const ushort* __restrict__ Hin,
                                                  const int2* __restrict__ sedge,
                                                  const int* __restrict__ rs,
                                                  const float* __restrict__ bias,
                                                  void* __restrict__ Hout, int N, int E) {
    int c = blockIdx.x * 4 + (threadIdx.x >> 6);
    if (c >= N) return;
    const int lane = threadIdx.x & 63;
    const int h  = lane >> 5;
    const int lq = lane & 31;

    float4 acc = make_float4(0.f, 0.f, 0.f, 0.f);
    if (bias && h == 0) acc = *(const float4*)&bias[lq * 4];

    const int e0 = rs[c];
    const int deg = rs[c + 1] - e0;

    for (int base = 0; base < deg; base += 64) {
        int m = min(64, deg - base);
        int idx = e0 + base + lane;
        int2 rec = sedge[idx < E ? idx : E - 1];

        int j = 0;
#define PLOAD(p, rr, ww, vv)                                                    \
        int   rr = __shfl(rec.x, j + 2 * (p) + h);                              \
        float ww = __int_as_float(__shfl(rec.y, j + 2 * (p) + h));              \
        uint2 vv = *(const uint2*)&Hin[(size_t)rr * 128 + lq * 4];
#define PACC(ww, vv)                                                            \
        acc.x = fmaf(ww, bflo(vv.x), acc.x); acc.y = fmaf(ww, bfhi(vv.x), acc.y);\
        acc.z = fmaf(ww, bflo(vv.y), acc.z); acc.w = fmaf(ww, bfhi(vv.y), acc.w);

        for (; j + 7 < m; j += 8) {
            PLOAD(0, r0, w0, v0) PLOAD(1, r1, w1, v1)
            PLOAD(2, r2, w2, v2) PLOAD(3, r3, w3, v3)
            PACC(w0, v0) PACC(w1, v1) PACC(w2, v2) PACC(w3, v3)
        }
        for (; j < m; j += 2) {
            int jj = j + h;
            int sl = (jj < m) ? jj : j;       // always < m: source lane active
            int   r0 = __shfl(rec.x, sl);     // unconditional shfl, full exec
            float w0 = __int_as_float(__shfl(rec.y, sl));
            if (jj >= m) w0 = 0.f;            // mask AFTER the cross-lane op
            uint2 v0 = *(const uint2*)&Hin[(size_t)r0 * 128 + lq * 4];
            PACC(w0, v0)
        }
#undef PLOAD
#undef PACC
    }

    acc.x += __shfl_xor(acc.x, 32);
    acc.y += __shfl_xor(acc.y, 32);
    acc.z += __shfl_xor(acc.z, 32);
    acc.w += __shfl_xor(acc.w, 32);

    if (h == 0) {
        if constexpr (OUT_BF16) {
            uint2 o;
            o.x = f2bf(acc.x) | ((uint)f2bf(acc.y) << 16);
            o.y = f2bf(acc.z) | ((uint)f2bf(acc.w) << 16);
            *(uint2*)&((uint*)Hout)[(size_t)c * 64 + lq * 2] = o;
        } else {
            *(float4*)&((float*)Hout)[(size_t)c * 128 + lq * 4] = acc;
        }
    }
}

// ================================================================= batchnorm stats (bf16 in)
__global__ __launch_bounds__(256) void bn_stats(const ushort* __restrict__ H,
                                                float* __restrict__ sums, int N) {
    int j = threadIdx.x & 127;
    float s = 0.f, s2 = 0.f;
    for (int n = blockIdx.x * 2 + (threadIdx.x >> 7); n < N; n += gridDim.x * 2) {
        float v = bf2f(H[(size_t)n * 128 + j]);
        s += v; s2 += v * v;
    }
    atomicAdd(&sums[j], s);
    atomicAdd(&sums[128 + j], s2);
}

// ================================================================= launch
extern "C" void kernel_launch(void* const* d_in, const int* in_sizes, int n_in,
                              void* d_out, int out_size, void* d_ws, size_t ws_size,
                              hipStream_t stream) {
    const float* x  = (const float*)d_in[0];
    const int*   ei = (const int*)d_in[1];
    const float* ew = (const float*)d_in[2];
    const float* W0 = (const float*)d_in[3];
    const float* W1 = (const float*)d_in[5];
    const float* b1 = (const float*)d_in[6];

    const int N = in_sizes[0] / 128;
    const int E = in_sizes[2];
    const int* row = ei;
    const int* col = ei + E;
    const int NB = (N + BKT - 1) >> BKT_SHIFT;  // 391 for N=100K (<=512 required)

    uintptr_t base = (uintptr_t)d_ws;
    auto alloc = [&](size_t bytes) {
        uintptr_t p = base;
        base += (bytes + 255) & ~(size_t)255;
        return (void*)p;
    };
    float*  dinv   = (float*) alloc((size_t)N * 4);
    float*  sums   = (float*) alloc(256 * 4);
    int*    bhist  = (int*)   alloc((size_t)(NB + 1) * 4);
    int*    bstart = (int*)   alloc((size_t)(NB + 1) * 4);
    int*    bcursor= (int*)   alloc((size_t)NB * 4);
    int*    rs     = (int*)   alloc((size_t)(N + 1) * 4);
    int2*   sedge  = (int2*)  alloc((size_t)E * 8);        // final {row, norm}
    ushort* hA     = (ushort*)alloc((size_t)N * 128 * 2);  // bf16 feature buffers
    ushort* hB     = (ushort*)alloc((size_t)N * 128 * 2);
    // brecs (bucket-partitioned temps) aliases hB: hB first written by conv1,
    // long after bucket_place consumed brecs.
    int2*   brecs  = (int2*)hB;
    float*  out    = (float*) d_out;
    (void)ws_size; (void)n_in; (void)out_size;

    const float invN = 1.f / (float)N;

    // per-call zeroing (harness does not re-poison between replays)
    hipMemsetAsync(bhist, 0, (size_t)(NB + 1) * 4, stream);
    hipMemsetAsync(sums, 0, 256 * 4, stream);

    // --- CSR build
    bucket_hist<<<1024, 512, 0, stream>>>(col, bhist, E, NB);
    scan_buckets<<<1, 512, 0, stream>>>(bhist, bstart, bcursor, rs, NB, N, E);
    bucket_scatter<<<(E + SC_E - 1) / SC_E, 512, 0, stream>>>(row, col, ew, bcursor,
                                                              brecs, E, NB);
    bucket_build_p1<<<NB, 256, 0, stream>>>(brecs, bstart, rs, dinv, N);
    bucket_place<<<NB, 256, 0, stream>>>(brecs, bstart, rs, dinv, sedge, N);

    const int nTiles = (N + 63) / 64;
    const int gemmGrid = nTiles < 512 ? nTiles : 512;

    // --- layer 0: hA(bf16) = x @ W0^T
    gemm128_mfma<0><<<gemmGrid, 256, 0, stream>>>(x, W0, hA, N, nullptr, 0.f);

    // --- conv 1: hB(bf16) = gather-reduce(hA)
    agg_gather<true><<<(N + 3) / 4, 256, 0, stream>>>(hA, sedge, rs, nullptr, hB, N, E);

    // --- BN stats on bf16 conv output (b0 cancels inside BN)
    bn_stats<<<512, 256, 0, stream>>>(hB, sums, N);

    // --- layer 1 (BN+ReLU fused into A-staging): hA(bf16) = relu(BN(hB)) @ W1^T
    gemm128_mfma<2><<<gemmGrid, 256, 0, stream>>>(hB, W1, hA, N, sums, invN);

    // --- conv 2 (+ b1): out(f32) = gather-reduce(hA) + b1
    agg_gather<false><<<(N + 3) / 4, 256, 0, stream>>>(hA, sedge, rs, b1, out, N, E);
}

// Round 11
// 291.918 us; speedup vs baseline: 5.8018x; 1.0057x over previous
//
#include <hip/hip_runtime.h>
#include <cstdint>
#include <cstddef>

#define EPSF 1e-5f
#define BKT 256
#define BKT_SHIFT 8
#define SC_E 4096

typedef unsigned long long ull;
typedef __attribute__((ext_vector_type(8))) short bf16x8;
typedef __attribute__((ext_vector_type(4))) float f32x4;

// ================================================================= CSR build
// Bucket = BKT consecutive destination nodes. NB = ceil(N/BKT) <= 512.
// meta = (colLow << 17) | row  (N <= 131072).

__global__ __launch_bounds__(512) void bucket_hist(const int* __restrict__ col,
                                                   int* __restrict__ bhist, int E, int NB) {
    __shared__ int lh[512];
    const int t = threadIdx.x;
    lh[t] = 0;
    __syncthreads();
    for (int e = blockIdx.x * 512 + t; e < E; e += gridDim.x * 512)
        atomicAdd(&lh[col[e] >> BKT_SHIFT], 1);
    __syncthreads();
    if (t < NB && lh[t]) atomicAdd(&bhist[t], lh[t]);
}

__global__ __launch_bounds__(512) void scan_buckets(const int* __restrict__ bhist,
                                                    int* __restrict__ bstart,
                                                    int* __restrict__ bcursor,
                                                    int* __restrict__ rs,
                                                    int NB, int N, int E) {
    __shared__ int part[512];
    const int t = threadIdx.x;
    part[t] = (t < NB) ? bhist[t] : 0;
    __syncthreads();
    for (int off = 1; off < 512; off <<= 1) {
        int v = (t >= off) ? part[t - off] : 0;
        __syncthreads();
        part[t] += v;
        __syncthreads();
    }
    int excl = (t == 0) ? 0 : part[t - 1];
    if (t < NB) { bstart[t] = excl; bcursor[t] = excl; }
    if (t == 0) { bstart[NB] = E; rs[N] = E; }
}

// multisplit scatter: LDS-sort a 4096-edge chunk by bucket, write runs contiguously
__global__ __launch_bounds__(512) void bucket_scatter(const int* __restrict__ row,
                                                      const int* __restrict__ col,
                                                      const float* __restrict__ w,
                                                      int* __restrict__ bcursor,
                                                      int2* __restrict__ brecs,
                                                      int E, int NB) {
    __shared__ int lh[512], lstart[512], lcur[512], gbase[512];
    __shared__ int   sm[SC_E];
    __shared__ float sw[SC_E];
    __shared__ short sb[SC_E];

    const int t = threadIdx.x;
    const int base = blockIdx.x * SC_E;
    const int cnt = min(SC_E, E - base);

    lh[t] = 0;
    __syncthreads();

    int   myb[8], mym[8];
    float myw[8];
#pragma unroll
    for (int k = 0; k < 8; ++k) {
        int i = t + k * 512;
        if (i < cnt) {
            int e = base + i;
            int r = row[e], c = col[e];
            myb[k] = c >> BKT_SHIFT;
            mym[k] = ((c & (BKT - 1)) << 17) | r;
            myw[k] = w[e];
            atomicAdd(&lh[myb[k]], 1);
        } else myb[k] = -1;
    }
    __syncthreads();

    int v = lh[t];
    lstart[t] = v;
    __syncthreads();
    for (int off = 1; off < 512; off <<= 1) {
        int u = (t >= off) ? lstart[t - off] : 0;
        __syncthreads();
        lstart[t] += u;
        __syncthreads();
    }
    int excl = lstart[t] - v;
    __syncthreads();
    lstart[t] = excl;
    lcur[t]   = excl;
    gbase[t]  = (t < NB) ? atomicAdd(&bcursor[t], v) : 0;
    __syncthreads();

#pragma unroll
    for (int k = 0; k < 8; ++k) {
        if (myb[k] >= 0) {
            int slot = atomicAdd(&lcur[myb[k]], 1);
            sm[slot] = mym[k];
            sw[slot] = myw[k];
            sb[slot] = (short)myb[k];
        }
    }
    __syncthreads();

    for (int j = t; j < cnt; j += 512) {
        int b = sb[j];
        int pos = gbase[b] + (j - lstart[b]);
        brecs[pos] = make_int2(sm[j], __float_as_int(sw[j]));
    }
}

// pass 1: per-node counts + weighted degree via LDS atomics -> rs, dinv
__global__ __launch_bounds__(256) void bucket_build_p1(const int2* __restrict__ brecs,
                                                       const int* __restrict__ bstart,
                                                       int* __restrict__ rs,
                                                       float* __restrict__ dinv, int N) {
    __shared__ int   lcnt[256], lscan[256];
    __shared__ float ldeg[256];
    const int b = blockIdx.x, t = threadIdx.x;
    const int s = bstart[b], e = bstart[b + 1];
    const int node0 = b << BKT_SHIFT;
    const int nNodes = min(BKT, N - node0);

    lcnt[t] = 0;
    ldeg[t] = 0.f;
    __syncthreads();

    for (int i = s + t; i < e; i += 256) {
        int2 r = brecs[i];
        int cl = r.x >> 17;
        atomicAdd(&lcnt[cl], 1);
        atomicAdd(&ldeg[cl], __int_as_float(r.y));
    }
    __syncthreads();

    int v = lcnt[t];
    lscan[t] = v;
    __syncthreads();
    for (int off = 1; off < 256; off <<= 1) {
        int u = (t >= off) ? lscan[t - off] : 0;
        __syncthreads();
        lscan[t] += u;
        __syncthreads();
    }
    if (t < nNodes) {
        rs[node0 + t] = s + (lscan[t] - v);
        float d = ldeg[t];
        dinv[node0 + t] = (d > 0.f) ? rsqrtf(d) : 0.f;
    }
}

// pass 2: node-sorted placement WITH norm computed in the same pass
__global__ __launch_bounds__(256) void bucket_place(const int2* __restrict__ brecs,
                                                    const int* __restrict__ bstart,
                                                    const int* __restrict__ rs,
                                                    const float* __restrict__ dinv,
                                                    int2* __restrict__ sedge, int N) {
    __shared__ int   lcur[256];
    __shared__ float ld[256];
    const int b = blockIdx.x, t = threadIdx.x;
    const int s = bstart[b], e = bstart[b + 1];
    const int node0 = b << BKT_SHIFT;
    const int nNodes = min(BKT, N - node0);

    lcur[t] = (t < nNodes) ? rs[node0 + t] : 0;
    ld[t]   = (t < nNodes) ? dinv[node0 + t] : 0.f;
    __syncthreads();

    for (int i = s + t; i < e; i += 256) {
        int2 r = brecs[i];
        int cl   = r.x >> 17;
        int rowi = r.x & 0x1FFFF;
        float nrm = dinv[rowi] * ld[cl] * __int_as_float(r.y);
        int slot = atomicAdd(&lcur[cl], 1);
        sedge[slot] = make_int2(rowi, __float_as_int(nrm));
    }
}

// ================================================================= GEMM (bf16 MFMA)
__device__ __forceinline__ ushort f2bf(float f) {
    uint b = __float_as_uint(f);
    return (ushort)((b + 0x7FFFu + ((b >> 16) & 1u)) >> 16);  // RNE
}
__device__ __forceinline__ float bf2f(ushort u) {
    return __uint_as_float((uint)u << 16);
}
__device__ __forceinline__ uint4 pack8(const float* f) {
    uint4 o;
    o.x = f2bf(f[0]) | ((uint)f2bf(f[1]) << 16);
    o.y = f2bf(f[2]) | ((uint)f2bf(f[3]) << 16);
    o.z = f2bf(f[4]) | ((uint)f2bf(f[5]) << 16);
    o.w = f2bf(f[6]) | ((uint)f2bf(f[7]) << 16);
    return o;
}

// Persistent-W: W (and BN prologue for MODE 2) staged ONCE per block; block then
// loops over row-tiles with stride gridDim.x.
template <int MODE>
__global__ __launch_bounds__(256) void gemm128_mfma(const void* __restrict__ Xv,
                                                    const float* __restrict__ W,
                                                    ushort* __restrict__ Y, int N,
                                                    const float* __restrict__ sums,
                                                    float invN) {
    __shared__ __align__(16) ushort Alds[64][128];
    __shared__ __align__(16) ushort Blds[128][128];
    __shared__ float bnmu[128], bnrs[128];

    const int t = threadIdx.x;

    if constexpr (MODE == 2) {
        if (t < 128) {
            float mu  = sums[t] * invN;
            float var = sums[128 + t] * invN - mu * mu;
            bnmu[t] = mu;
            bnrs[t] = rsqrtf(var + EPSF);
        }
    }

    for (int i = t; i < 128 * 16; i += 256) {
        int j = i >> 4, kc = (i & 15) << 3;
        float f[8];
        *(float4*)&f[0] = *(const float4*)&W[j * 128 + kc];
        *(float4*)&f[4] = *(const float4*)&W[j * 128 + kc + 4];
        *(uint4*)&Blds[j][kc ^ ((j & 7) << 3)] = pack8(f);
    }

    const int lane  = t & 63;
    const int wv    = t >> 6;
    const int arow  = wv * 16 + (lane & 15);
    const int klane = (lane >> 4) << 3;
    const int cq    = lane & 15;
    const int nTiles = (N + 63) >> 6;

    for (int tile = blockIdx.x; tile < nTiles; tile += gridDim.x) {
        const int n0 = tile * 64;
        __syncthreads();  // W/bnmu visible (1st iter); prior MFMA reads done (later)

        for (int i = t; i < 64 * 16; i += 256) {
            int r = i >> 4, kc = (i & 15) << 3;
            int n = n0 + r;
            uint4 v = make_uint4(0u, 0u, 0u, 0u);
            if (n < N) {
                if constexpr (MODE == 0) {
                    float f[8];
                    *(float4*)&f[0] = *(const float4*)&((const float*)Xv)[(size_t)n * 128 + kc];
                    *(float4*)&f[4] = *(const float4*)&((const float*)Xv)[(size_t)n * 128 + kc + 4];
                    v = pack8(f);
                } else {
                    uint4 raw = *(const uint4*)&((const ushort*)Xv)[(size_t)n * 128 + kc];
                    const uint* rw = &raw.x;
                    float f[8];
#pragma unroll
                    for (int k = 0; k < 4; ++k) {
                        float lo = __uint_as_float(rw[k] << 16);
                        float hi = __uint_as_float(rw[k] & 0xFFFF0000u);
                        f[2 * k]     = fmaxf((lo - bnmu[kc + 2 * k])     * bnrs[kc + 2 * k],     0.f);
                        f[2 * k + 1] = fmaxf((hi - bnmu[kc + 2 * k + 1]) * bnrs[kc + 2 * k + 1], 0.f);
                    }
                    v = pack8(f);
                }
            }
            *(uint4*)&Alds[r][kc ^ ((r & 7) << 3)] = v;
        }
        __syncthreads();

        f32x4 acc[8] = {};
        for (int ks = 0; ks < 4; ++ks) {
            const int k0 = ks * 32 + klane;
            bf16x8 a = *(const bf16x8*)&Alds[arow][k0 ^ ((arow & 7) << 3)];
#pragma unroll
            for (int tl = 0; tl < 8; ++tl) {
                int colr = tl * 16 + cq;
                bf16x8 bb = *(const bf16x8*)&Blds[colr][k0 ^ ((colr & 7) << 3)];
                acc[tl] = __builtin_amdgcn_mfma_f32_16x16x32_bf16(a, bb, acc[tl], 0, 0, 0);
            }
        }

        const int r0 = n0 + wv * 16 + ((lane >> 4) << 2);
#pragma unroll
        for (int tl = 0; tl < 8; ++tl) {
#pragma unroll
            for (int reg = 0; reg < 4; ++reg) {
                int rr = r0 + reg;
                if (rr < N) Y[(size_t)rr * 128 + tl * 16 + cq] = f2bf(acc[tl][reg]);
            }
        }
    }
}

// ================================================================= gather conv
// one wave per dest node. Quarter-wave grouping: quarter g (16 lanes), lane lq
// holds features [8lq..8lq+8) of edge (j+g) via ONE uint4 load -> one vmem op
// moves 4 full 256B rows; 16-edge unroll keeps 4 loads (4KB) in flight.
// All __shfl ops unconditional with in-range sources (round-9 lesson).
// Final reduce: shfl_xor(16) + shfl_xor(32) sums the 4 quarters.
__device__ __forceinline__ float bflo(uint v) { return __uint_as_float(v << 16); }
__device__ __forceinline__ float bfhi(uint v) { return __uint_as_float(v & 0xFFFF0000u); }

template <bool OUT_BF16>
__global__ __launch_bounds__(256) void agg_gather(const ushort* __restrict__ Hin,
                                                  const int2* __restrict__ sedge,
                                                  const int* __restrict__ rs,
                                                  const float* __restrict__ bias,
                                                  void* __restrict__ Hout, int N, int E) {
    int c = blockIdx.x * 4 + (threadIdx.x >> 6);
    if (c >= N) return;
    const int lane = threadIdx.x & 63;
    const int g  = lane >> 4;   // quarter id 0..3
    const int lq = lane & 15;   // lane within quarter

    float acc[8] = {0.f, 0.f, 0.f, 0.f, 0.f, 0.f, 0.f, 0.f};
    if (bias && g == 0) {
        *(float4*)&acc[0] = *(const float4*)&bias[lq * 8];
        *(float4*)&acc[4] = *(const float4*)&bias[lq * 8 + 4];
    }

    const int e0 = rs[c];
    const int deg = rs[c + 1] - e0;

    for (int base = 0; base < deg; base += 64) {
        int m = min(64, deg - base);
        int idx = e0 + base + lane;
        int2 rec = sedge[idx < E ? idx : E - 1];

        int j = 0;
#define QLOAD(p, rr, ww, vv)                                                    \
        int   rr = __shfl(rec.x, j + 4 * (p) + g);                              \
        float ww = __int_as_float(__shfl(rec.y, j + 4 * (p) + g));              \
        uint4 vv = *(const uint4*)&Hin[(size_t)rr * 128 + lq * 8];
#define QACC(ww, vv)                                                            \
        acc[0] = fmaf(ww, bflo(vv.x), acc[0]); acc[1] = fmaf(ww, bfhi(vv.x), acc[1]); \
        acc[2] = fmaf(ww, bflo(vv.y), acc[2]); acc[3] = fmaf(ww, bfhi(vv.y), acc[3]); \
        acc[4] = fmaf(ww, bflo(vv.z), acc[4]); acc[5] = fmaf(ww, bfhi(vv.z), acc[5]); \
        acc[6] = fmaf(ww, bflo(vv.w), acc[6]); acc[7] = fmaf(ww, bfhi(vv.w), acc[7]);

        for (; j + 15 < m; j += 16) {
            QLOAD(0, r0, w0, v0) QLOAD(1, r1, w1, v1)
            QLOAD(2, r2, w2, v2) QLOAD(3, r3, w3, v3)
            QACC(w0, v0) QACC(w1, v1) QACC(w2, v2) QACC(w3, v3)
        }
        for (; j < m; j += 4) {
            int jj = j + g;
            int sl = (jj < m) ? jj : j;       // always < m: source lane active
            int   r0 = __shfl(rec.x, sl);     // unconditional shfl, full exec
            float w0 = __int_as_float(__shfl(rec.y, sl));
            if (jj >= m) w0 = 0.f;            // mask AFTER the cross-lane op
            uint4 v0 = *(const uint4*)&Hin[(size_t)r0 * 128 + lq * 8];
            QACC(w0, v0)
        }
#undef QLOAD
#undef QACC
    }

#pragma unroll
    for (int k = 0; k < 8; ++k) {
        acc[k] += __shfl_xor(acc[k], 16);
        acc[k] += __shfl_xor(acc[k], 32);
    }

    if (g == 0) {
        if constexpr (OUT_BF16) {
            uint4 o;
            o.x = f2bf(acc[0]) | ((uint)f2bf(acc[1]) << 16);
            o.y = f2bf(acc[2]) | ((uint)f2bf(acc[3]) << 16);
            o.z = f2bf(acc[4]) | ((uint)f2bf(acc[5]) << 16);
            o.w = f2bf(acc[6]) | ((uint)f2bf(acc[7]) << 16);
            *(uint4*)&((uint*)Hout)[(size_t)c * 64 + lq * 4] = o;
        } else {
            *(float4*)&((float*)Hout)[(size_t)c * 128 + lq * 8]     = *(float4*)&acc[0];
            *(float4*)&((float*)Hout)[(size_t)c * 128 + lq * 8 + 4] = *(float4*)&acc[4];
        }
    }
}

// ================================================================= batchnorm stats (bf16 in)
__global__ __launch_bounds__(256) void bn_stats(const ushort* __restrict__ H,
                                                float* __restrict__ sums, int N) {
    int j = threadIdx.x & 127;
    float s = 0.f, s2 = 0.f;
    for (int n = blockIdx.x * 2 + (threadIdx.x >> 7); n < N; n += gridDim.x * 2) {
        float v = bf2f(H[(size_t)n * 128 + j]);
        s += v; s2 += v * v;
    }
    atomicAdd(&sums[j], s);
    atomicAdd(&sums[128 + j], s2);
}

// ================================================================= launch
extern "C" void kernel_launch(void* const* d_in, const int* in_sizes, int n_in,
                              void* d_out, int out_size, void* d_ws, size_t ws_size,
                              hipStream_t stream) {
    const float* x  = (const float*)d_in[0];
    const int*   ei = (const int*)d_in[1];
    const float* ew = (const float*)d_in[2];
    const float* W0 = (const float*)d_in[3];
    const float* W1 = (const float*)d_in[5];
    const float* b1 = (const float*)d_in[6];

    const int N = in_sizes[0] / 128;
    const int E = in_sizes[2];
    const int* row = ei;
    const int* col = ei + E;
    const int NB = (N + BKT - 1) >> BKT_SHIFT;  // 391 for N=100K (<=512 required)

    uintptr_t base = (uintptr_t)d_ws;
    auto alloc = [&](size_t bytes) {
        uintptr_t p = base;
        base += (bytes + 255) & ~(size_t)255;
        return (void*)p;
    };
    float*  dinv   = (float*) alloc((size_t)N * 4);
    float*  sums   = (float*) alloc(256 * 4);
    int*    bhist  = (int*)   alloc((size_t)(NB + 1) * 4);
    int*    bstart = (int*)   alloc((size_t)(NB + 1) * 4);
    int*    bcursor= (int*)   alloc((size_t)NB * 4);
    int*    rs     = (int*)   alloc((size_t)(N + 1) * 4);
    int2*   sedge  = (int2*)  alloc((size_t)E * 8);        // final {row, norm}
    ushort* hA     = (ushort*)alloc((size_t)N * 128 * 2);  // bf16 feature buffers
    ushort* hB     = (ushort*)alloc((size_t)N * 128 * 2);
    // brecs (bucket-partitioned temps) aliases hB: hB first written by conv1,
    // long after bucket_place consumed brecs.
    int2*   brecs  = (int2*)hB;
    float*  out    = (float*) d_out;
    (void)ws_size; (void)n_in; (void)out_size;

    const float invN = 1.f / (float)N;

    // per-call zeroing (harness does not re-poison between replays)
    hipMemsetAsync(bhist, 0, (size_t)(NB + 1) * 4, stream);
    hipMemsetAsync(sums, 0, 256 * 4, stream);

    // --- CSR build
    bucket_hist<<<1024, 512, 0, stream>>>(col, bhist, E, NB);
    scan_buckets<<<1, 512, 0, stream>>>(bhist, bstart, bcursor, rs, NB, N, E);
    bucket_scatter<<<(E + SC_E - 1) / SC_E, 512, 0, stream>>>(row, col, ew, bcursor,
                                                              brecs, E, NB);
    bucket_build_p1<<<NB, 256, 0, stream>>>(brecs, bstart, rs, dinv, N);
    bucket_place<<<NB, 256, 0, stream>>>(brecs, bstart, rs, dinv, sedge, N);

    const int nTiles = (N + 63) / 64;
    const int gemmGrid = nTiles < 512 ? nTiles : 512;

    // --- layer 0: hA(bf16) = x @ W0^T
    gemm128_mfma<0><<<gemmGrid, 256, 0, stream>>>(x, W0, hA, N, nullptr, 0.f);

    // --- conv 1: hB(bf16) = gather-reduce(hA)
    agg_gather<true><<<(N + 3) / 4, 256, 0, stream>>>(hA, sedge, rs, nullptr, hB, N, E);

    // --- BN stats on bf16 conv output (b0 cancels inside BN)
    bn_stats<<<512, 256, 0, stream>>>(hB, sums, N);

    // --- layer 1 (BN+ReLU fused into A-staging): hA(bf16) = relu(BN(hB)) @ W1^T
    gemm128_mfma<2><<<gemmGrid, 256, 0, stream>>>(hB, W1, hA, N, sums, invN);

    // --- conv 2 (+ b1): out(f32) = gather-reduce(hA) + b1
    agg_gather<false><<<(N + 3) / 4, 256, 0, stream>>>(hA, sedge, rs, b1, out, N, E);
}